// Round 6
// baseline (1475.014 us; speedup 1.0000x reference)
//
#include <hip/hip_runtime.h>
#include <math.h>

#define N_RELS 1315
#define NB 65536
#define NNZV (1 << 20)
#define FEATD 768

#define NBUK 256       // row buckets (256 rows each)
#define CAP  5120      // bin capacity per (matrix,bucket); expected 4096, sigma 64
#define CHUNK 4096     // edges per k_bin block
#define STG  2048      // edges per stage
#define EPT  8         // edges per thread per stage (256 threads)
#define TILE 1024      // edges staged in LDS per k_acc tile

typedef float f32x4 __attribute__((ext_vector_type(4)));
typedef short s16x8 __attribute__((ext_vector_type(8)));
typedef float v2f  __attribute__((ext_vector_type(2)));

struct Mats { const int* rows[6]; const int* cols[6]; const float* vals[6]; };

__device__ __forceinline__ short f2bf(float f) {
    return __builtin_bit_cast(short, (__bf16)f);
}

// ---------------- precompute: P tables, Prel, b' ----------------
__global__ void k_prep(const float* __restrict__ rel_emb,
                       const float* __restrict__ W_in, const float* __restrict__ b_in,
                       const float* __restrict__ W_out, const float* __restrict__ b_out,
                       const float* __restrict__ W_ent, const float* __restrict__ b_ent,
                       const float* __restrict__ W_rel, const float* __restrict__ b_rel,
                       float* __restrict__ Pcat, float* __restrict__ Prel,
                       float* __restrict__ bprime)
{
    __shared__ float C[2][32][33];
    const int tid = threadIdx.x;
    for (int idx = tid; idx < 2 * 32 * 32; idx += 256) {
        int d = idx >> 10, o = (idx >> 5) & 31, t = idx & 31;
        const float* W  = d ? W_out : W_in;
        const float* we = W_ent + o * 832 + 768 + d * 32;
        float s = 0.f;
        #pragma unroll
        for (int j = 0; j < 32; ++j) s += we[j] * W[j * 32 + t];
        C[d][o][t] = s;
    }
    __syncthreads();

    const int row8 = blockIdx.x * 8 + (tid >> 5);
    const int o = tid & 31;
    if (row8 < 2 * N_RELS) {
        const int d = (row8 >= N_RELS) ? 1 : 0;
        const int r = row8 - d * N_RELS;
        const float* re = rel_emb + r * 32;
        float s = 0.f;
        #pragma unroll
        for (int t = 0; t < 32; ++t) s += re[t] * C[d][o][t];
        Pcat[row8 * 32 + o] = s;
    } else if (row8 < 3 * N_RELS) {
        const int r = row8 - 2 * N_RELS;
        const float* re = rel_emb + r * 32;
        float s = b_rel[o];
        #pragma unroll
        for (int j = 0; j < 32; ++j) s += W_rel[o * 32 + j] * re[j];
        float sq = s * s;
        #pragma unroll
        for (int m = 16; m; m >>= 1) sq += __shfl_xor(sq, m);
        Prel[r * 32 + o] = s / fmaxf(sqrtf(sq), 1e-12f);
    }
    if (blockIdx.x == 0 && tid < 32) {
        float s = b_ent[tid];
        #pragma unroll
        for (int j = 0; j < 32; ++j)
            s += b_in[j] * W_ent[tid * 832 + 768 + j] + b_out[j] * W_ent[tid * 832 + 800 + j];
        bprime[tid] = s;
    }
}

// ---------------- pack W_ent[:, :768] into bf16 B-fragments ----------------
__global__ void k_wfrag(const float* __restrict__ W_ent, s16x8* __restrict__ wsB)
{
    const int t = blockIdx.x * 256 + threadIdx.x;
    if (t >= 24 * 2 * 64) return;
    const int kk = t >> 7, rem = t & 127, nt = rem >> 6, l = rem & 63;
    const int col = nt * 16 + (l & 15);
    const int k0  = kk * 32 + ((l >> 4) << 3);
    const float* w = W_ent + col * 832 + k0;
    s16x8 v;
    #pragma unroll
    for (int e = 0; e < 8; ++e) v[e] = f2bf(w[e]);
    wsB[t] = v;
}

// ---------------- cursor init ----------------
__global__ void k_cursor(unsigned* __restrict__ cursor)
{
    const int i = blockIdx.x * 256 + threadIdx.x;
    if (i < 6 * NBUK) cursor[i] = (unsigned)i * CAP;
}

// ---------------- bin edges by row bucket ----------------
__global__ __launch_bounds__(256) void k_bin(Mats m, uint2* __restrict__ bins,
                                             unsigned* __restrict__ cursor)
{
    __shared__ unsigned lcnt[NBUK];
    __shared__ unsigned gbase[NBUK];
    const int mm    = blockIdx.x >> 8;      // 6 matrices x 256 chunks
    const int chunk = blockIdx.x & 255;
    const int tid   = threadIdx.x;
    const int* __restrict__ R = m.rows[mm];
    const int* __restrict__ C = m.cols[mm];
    const float* __restrict__ V = m.vals[mm];
    const int base = chunk * CHUNK;

    for (int st = 0; st < CHUNK / STG; ++st) {
        for (int i = tid; i < NBUK; i += 256) lcnt[i] = 0;
        __syncthreads();
        unsigned meta[EPT]; float val[EPT]; unsigned short lrank[EPT]; unsigned char buk[EPT];
        #pragma unroll
        for (int e = 0; e < EPT; ++e) {
            const int idx = base + st * STG + e * 256 + tid;
            const int row = R[idx];
            const int col = C[idx];
            val[e]  = V[idx];
            buk[e]  = (unsigned char)(row >> 8);
            meta[e] = ((unsigned)(row & 255) << 11) | (unsigned)col;
            lrank[e] = (unsigned short)atomicAdd(&lcnt[buk[e]], 1u);
        }
        __syncthreads();
        gbase[tid] = atomicAdd(&cursor[mm * NBUK + tid], lcnt[tid]);
        __syncthreads();
        #pragma unroll
        for (int e = 0; e < EPT; ++e)
            bins[gbase[buk[e]] + lrank[e]] = make_uint2(meta[e], __float_as_uint(val[e]));
        __syncthreads();
    }
}

// ---------------- per-bucket LDS reduce: aggY[set][rows of bucket] ----------------
// Tile of 1024 edges staged in LDS (coalesced, dependence-free), then each
// 16-thread group processes 8 edges at a time through explicit register
// arrays: 8 independent LDS meta reads -> 8 independent P loads in flight ->
// 16 fire-and-forget ds_add_f32. Compile-time trip counts force the unroll.
__global__ __launch_bounds__(512) void k_acc(const uint2* __restrict__ bins,
                                             const unsigned* __restrict__ cursor,
                                             const float* __restrict__ Pcat,
                                             float* __restrict__ aggY)
{
    __shared__ float acc[256 * 32];   // 32 KB
    __shared__ uint2 stage[TILE];     // 8 KB
    const int set = blockIdx.x >> 8;  // 3 sets x 256 buckets
    const int b   = blockIdx.x & 255;
    const int tid = threadIdx.x;
    for (int i = tid; i < 256 * 32; i += 512) acc[i] = 0.f;

    const int eg = tid >> 4;          // edge-group 0..31 (16 threads each)
    const int c2 = (tid & 15) << 1;   // component pair
    for (int dir = 0; dir < 2; ++dir) {
        const int mm = set * 2 + dir;
        const unsigned segbase = (unsigned)(mm * NBUK + b) * CAP;
        const uint2* __restrict__ seg = bins + segbase;
        const int len = (int)(cursor[mm * NBUK + b] - segbase);
        const float* __restrict__ P = Pcat + (size_t)dir * N_RELS * 32;

        for (int t0 = 0; t0 < len; t0 += TILE) {
            const int cnt = min(TILE, len - t0);
            __syncthreads();                 // protect stage (and acc on first pass)
            for (int i = tid; i < cnt; i += 512) stage[i] = seg[t0 + i];
            __syncthreads();
            // 32 edges per group, in 4 batches of 8
            #pragma unroll
            for (int k0 = 0; k0 < 32; k0 += 8) {
                uint2 e[8];
                #pragma unroll
                for (int j = 0; j < 8; ++j) {
                    const int idx = (k0 + j) * 32 + eg;
                    e[j] = stage[idx < cnt ? idx : 0];
                    if (idx >= cnt) e[j].y = 0;   // val = 0 -> no-op
                }
                float2 pv[8];
                #pragma unroll
                for (int j = 0; j < 8; ++j)
                    pv[j] = *reinterpret_cast<const float2*>(P + ((e[j].x & 2047u) << 5) + c2);
                #pragma unroll
                for (int j = 0; j < 8; ++j) {
                    const float v = __uint_as_float(e[j].y);
                    float* dst = &acc[((e[j].x >> 11) << 5) + c2];
                    atomicAdd(dst,     v * pv[j].x);
                    atomicAdd(dst + 1, v * pv[j].y);
                }
            }
        }
    }
    __syncthreads();
    // exclusive coalesced store
    float4* dst4 = reinterpret_cast<float4*>(aggY + ((size_t)set * NB + (size_t)b * 256) * 32);
    const float4* src = reinterpret_cast<const float4*>(acc);
    for (int i = tid; i < 2048; i += 512) dst4[i] = src[i];
}

// ---------------- fallback scatter (ws too small) ----------------
__global__ void k_scatter(const int* __restrict__ rows, const int* __restrict__ cols,
                          const float* __restrict__ vals,
                          const float* __restrict__ Ptab, float* __restrict__ accs)
{
    const int stride = gridDim.x * blockDim.x;
    const int total = NNZV << 4;
    for (int g = blockIdx.x * blockDim.x + threadIdx.x; g < total; g += stride) {
        const int c2 = (g & 15) << 1;
        const int i  = g >> 4;
        const int row = rows[i];
        const int col = cols[i];
        const float v = vals[i];
        const float* p = Ptab + (col << 5) + c2;
        const int dst = (row << 5) + c2;
#if defined(__has_builtin) && __has_builtin(__builtin_amdgcn_global_atomic_fadd_v2f32)
        typedef __attribute__((address_space(1))) v2f* v2f_as1;
        v2f pv; pv.x = v * p[0]; pv.y = v * p[1];
        __builtin_amdgcn_global_atomic_fadd_v2f32(
            (v2f_as1)(unsigned long long)(accs + dst), pv);
#else
        atomicAdd(accs + dst,     v * p[0]);
        atomicAdd(accs + dst + 1, v * p[1]);
#endif
    }
}

// ---------------- GEMM: Y[set] = normalize(feat @ W.T + b' + agg) ----------------
__global__ __launch_bounds__(256) void k_gemm(
    const float* __restrict__ feat_h, const float* __restrict__ feat_p,
    const float* __restrict__ feat_n,
    const s16x8* __restrict__ wsB, const float* __restrict__ bprime,
    float* __restrict__ Y)
{
    const int lane = threadIdx.x & 63;
    const int wid  = blockIdx.x * 4 + (threadIdx.x >> 6);
    const int set  = wid >> 12;
    const int tile = wid & 4095;
    const int e0   = tile << 4;
    const float* feat = (set == 0) ? feat_h : ((set == 1) ? feat_p : feat_n);

    const int l15 = lane & 15;
    const int kq  = lane >> 4;

    const float4* ap4 = reinterpret_cast<const float4*>(
        feat + (size_t)(e0 + l15) * FEATD + (kq << 3));
    const s16x8* bp = wsB + lane;

    f32x4 acc0 = {0.f, 0.f, 0.f, 0.f};
    f32x4 acc1 = {0.f, 0.f, 0.f, 0.f};

    float4 a0 = ap4[0], a1 = ap4[1];
    #pragma unroll 4
    for (int kk = 0; kk < 24; ++kk) {
        float4 n0, n1;
        if (kk < 23) { n0 = ap4[(kk + 1) * 8]; n1 = ap4[(kk + 1) * 8 + 1]; }
        const s16x8 b0 = bp[(kk * 2 + 0) << 6];
        const s16x8 b1 = bp[(kk * 2 + 1) << 6];
        s16x8 av;
        av[0] = f2bf(a0.x); av[1] = f2bf(a0.y); av[2] = f2bf(a0.z); av[3] = f2bf(a0.w);
        av[4] = f2bf(a1.x); av[5] = f2bf(a1.y); av[6] = f2bf(a1.z); av[7] = f2bf(a1.w);
        acc0 = __builtin_amdgcn_mfma_f32_16x16x32_bf16(av, b0, acc0, 0, 0, 0);
        acc1 = __builtin_amdgcn_mfma_f32_16x16x32_bf16(av, b1, acc1, 0, 0, 0);
        a0 = n0; a1 = n1;
    }

    float* yrow = Y + (size_t)set * NB * 32;
    const float bp0 = bprime[l15], bp1 = bprime[l15 + 16];
    const int rbase = e0 + (kq << 2);
    #pragma unroll
    for (int e = 0; e < 4; ++e) {
        const int ent = rbase + e;
        float v0 = acc0[e] + bp0 + yrow[ent * 32 + l15];
        float v1 = acc1[e] + bp1 + yrow[ent * 32 + l15 + 16];
        float sq = v0 * v0 + v1 * v1;
        sq += __shfl_xor(sq, 1);
        sq += __shfl_xor(sq, 2);
        sq += __shfl_xor(sq, 4);
        sq += __shfl_xor(sq, 8);
        const float inv = 1.f / fmaxf(sqrtf(sq), 1e-12f);
        yrow[ent * 32 + l15]      = v0 * inv;
        yrow[ent * 32 + l15 + 16] = v1 * inv;
    }
}

// ---------------- scores ----------------
__global__ __launch_bounds__(256) void k_score(const float* __restrict__ Y,
                                               const int* __restrict__ eid,
                                               const float* __restrict__ Prel,
                                               float* __restrict__ out)
{
    const int tid = blockIdx.x * 256 + threadIdx.x;
    const int ent = tid >> 5;
    const int c   = tid & 31;
    const float yh = Y[((size_t)0 * NB + ent) * 32 + c];
    const float yp = Y[((size_t)1 * NB + ent) * 32 + c];
    const float yn = Y[((size_t)2 * NB + ent) * 32 + c];
    const float r  = Prel[(size_t)eid[ent] * 32 + c];
    const float dp = yh + r - yp;
    const float dn = yh + r - yn;
    float sp = dp * dp, sn = dn * dn;
    #pragma unroll
    for (int m = 1; m <= 16; m <<= 1) { sp += __shfl_xor(sp, m); sn += __shfl_xor(sn, m); }
    if (c == 0) { out[ent] = sqrtf(sp); out[NB + ent] = sqrtf(sn); }
}

extern "C" void kernel_launch(void* const* d_in, const int* in_sizes, int n_in,
                              void* d_out, int out_size, void* d_ws, size_t ws_size,
                              hipStream_t stream)
{
    const float* feat_h = (const float*)d_in[6];
    const float* feat_p = (const float*)d_in[13];
    const float* feat_n = (const float*)d_in[20];
    const int*   eid    = (const int*)d_in[21];
    const float* rel_emb = (const float*)d_in[22];
    const float* W_in  = (const float*)d_in[23];
    const float* b_in  = (const float*)d_in[24];
    const float* W_out = (const float*)d_in[25];
    const float* b_out = (const float*)d_in[26];
    const float* W_ent = (const float*)d_in[27];
    const float* b_ent = (const float*)d_in[28];
    const float* W_rel = (const float*)d_in[29];
    const float* b_rel = (const float*)d_in[30];

    char* ws = (char*)d_ws;
    const size_t AGG_B   = (size_t)3 * NB * 32 * 4;          // 25,165,824
    const size_t BINS_B  = (size_t)6 * NBUK * CAP * 8;       // 62,914,560
    const size_t CURS_B  = (size_t)6 * NBUK * 4;
    const size_t PCAT_B  = (size_t)2 * N_RELS * 32 * 4;
    const size_t PREL_B  = (size_t)N_RELS * 32 * 4;
    const size_t BPR_B   = 128;
    const size_t WSB_B   = (size_t)24 * 2 * 64 * 16;
    const bool fast = ws_size >= AGG_B + BINS_B + CURS_B + PCAT_B + PREL_B + BPR_B + WSB_B;

    float*    aggY   = (float*)ws;
    size_t off = AGG_B;
    uint2*    bins   = nullptr;
    unsigned* cursor = nullptr;
    if (fast) { bins = (uint2*)(ws + off); off += BINS_B;
                cursor = (unsigned*)(ws + off); off += CURS_B; }
    float* Pcat   = (float*)(ws + off); off += PCAT_B;
    float* Prel   = (float*)(ws + off); off += PREL_B;
    float* bprime = (float*)(ws + off); off += BPR_B;
    s16x8* wsB    = (s16x8*)(ws + off);

    k_prep<<<(3 * N_RELS + 7) / 8, 256, 0, stream>>>(rel_emb, W_in, b_in, W_out, b_out,
                                                     W_ent, b_ent, W_rel, b_rel,
                                                     Pcat, Prel, bprime);
    k_wfrag<<<12, 256, 0, stream>>>(W_ent, wsB);

    static const int base_idx[6] = {0, 3, 7, 10, 14, 17};
    if (fast) {
        Mats m;
        for (int i = 0; i < 6; ++i) {
            m.rows[i] = (const int*)d_in[base_idx[i]];
            m.cols[i] = (const int*)d_in[base_idx[i] + 1];
            m.vals[i] = (const float*)d_in[base_idx[i] + 2];
        }
        k_cursor<<<6, 256, 0, stream>>>(cursor);
        k_bin<<<6 * 256, 256, 0, stream>>>(m, bins, cursor);
        k_acc<<<3 * 256, 512, 0, stream>>>(bins, cursor, Pcat, aggY);
    } else {
        hipMemsetAsync(aggY, 0, AGG_B, stream);
        for (int mm = 0; mm < 6; ++mm) {
            const int d = mm & 1, s = mm >> 1;
            k_scatter<<<32768, 256, 0, stream>>>((const int*)d_in[base_idx[mm]],
                                                 (const int*)d_in[base_idx[mm] + 1],
                                                 (const float*)d_in[base_idx[mm] + 2],
                                                 Pcat + (size_t)d * N_RELS * 32,
                                                 aggY + (size_t)s * NB * 32);
        }
    }

    k_gemm<<<3072, 256, 0, stream>>>(feat_h, feat_p, feat_n, wsB, bprime, aggY);
    k_score<<<8192, 256, 0, stream>>>(aggY, eid, Prel, (float*)d_out);
}

// Round 7
// 1025.010 us; speedup vs baseline: 1.4390x; 1.4390x over previous
//
#include <hip/hip_runtime.h>
#include <math.h>

#define N_RELS 1315
#define NB 65536
#define NNZV (1 << 20)
#define FEATD 768

typedef float f32x4 __attribute__((ext_vector_type(4)));
typedef short s16x8 __attribute__((ext_vector_type(8)));
typedef float v2f  __attribute__((ext_vector_type(2)));

struct Mats { const int* rows[6]; const int* cols[6]; const float* vals[6]; };

__device__ __forceinline__ short f2bf(float f) {
    return __builtin_bit_cast(short, (__bf16)f);
}

// ---------------- precompute: P tables, Prel, b' ----------------
__global__ void k_prep(const float* __restrict__ rel_emb,
                       const float* __restrict__ W_in, const float* __restrict__ b_in,
                       const float* __restrict__ W_out, const float* __restrict__ b_out,
                       const float* __restrict__ W_ent, const float* __restrict__ b_ent,
                       const float* __restrict__ W_rel, const float* __restrict__ b_rel,
                       float* __restrict__ Pcat, float* __restrict__ Prel,
                       float* __restrict__ bprime)
{
    __shared__ float C[2][32][33];
    const int tid = threadIdx.x;
    for (int idx = tid; idx < 2 * 32 * 32; idx += 256) {
        int d = idx >> 10, o = (idx >> 5) & 31, t = idx & 31;
        const float* W  = d ? W_out : W_in;
        const float* we = W_ent + o * 832 + 768 + d * 32;
        float s = 0.f;
        #pragma unroll
        for (int j = 0; j < 32; ++j) s += we[j] * W[j * 32 + t];
        C[d][o][t] = s;
    }
    __syncthreads();

    const int row8 = blockIdx.x * 8 + (tid >> 5);
    const int o = tid & 31;
    if (row8 < 2 * N_RELS) {
        const int d = (row8 >= N_RELS) ? 1 : 0;
        const int r = row8 - d * N_RELS;
        const float* re = rel_emb + r * 32;
        float s = 0.f;
        #pragma unroll
        for (int t = 0; t < 32; ++t) s += re[t] * C[d][o][t];
        Pcat[row8 * 32 + o] = s;
    } else if (row8 < 3 * N_RELS) {
        const int r = row8 - 2 * N_RELS;
        const float* re = rel_emb + r * 32;
        float s = b_rel[o];
        #pragma unroll
        for (int j = 0; j < 32; ++j) s += W_rel[o * 32 + j] * re[j];
        float sq = s * s;
        #pragma unroll
        for (int m = 16; m; m >>= 1) sq += __shfl_xor(sq, m);
        Prel[r * 32 + o] = s / fmaxf(sqrtf(sq), 1e-12f);
    }
    if (blockIdx.x == 0 && tid < 32) {
        float s = b_ent[tid];
        #pragma unroll
        for (int j = 0; j < 32; ++j)
            s += b_in[j] * W_ent[tid * 832 + 768 + j] + b_out[j] * W_ent[tid * 832 + 800 + j];
        bprime[tid] = s;
    }
}

// ---------------- pack W_ent[:, :768] into bf16 B-fragments ----------------
__global__ void k_wfrag(const float* __restrict__ W_ent, s16x8* __restrict__ wsB)
{
    const int t = blockIdx.x * 256 + threadIdx.x;
    if (t >= 24 * 2 * 64) return;
    const int kk = t >> 7, rem = t & 127, nt = rem >> 6, l = rem & 63;
    const int col = nt * 16 + (l & 15);
    const int k0  = kk * 32 + ((l >> 4) << 3);
    const float* w = W_ent + col * 832 + k0;
    s16x8 v;
    #pragma unroll
    for (int e = 0; e < 8; ++e) v[e] = f2bf(w[e]);
    wsB[t] = v;
}

// ---------------- CSR build: count ----------------
__global__ __launch_bounds__(256) void k_count(Mats m, int* __restrict__ cnt)
{
    const int g  = blockIdx.x * 256 + threadIdx.x;   // 6*NNZV threads
    const int mm = g >> 20;
    const int i  = g & (NNZV - 1);
    atomicAdd(&cnt[mm * NB + m.rows[mm][i]], 1);
}

// ---------------- scan level 1: 1024 entries per block ----------------
__global__ __launch_bounds__(256) void k_scan1(const int* __restrict__ cnt,
                                               int* __restrict__ csr,
                                               int* __restrict__ bsum)
{
    __shared__ int sdata[256];
    const int blk = blockIdx.x, t = threadIdx.x;
    const int base = blk * 1024 + t * 4;
    int4 v = *(const int4*)(cnt + base);
    const int s0 = v.x, s1 = s0 + v.y, s2 = s1 + v.z, s3 = s2 + v.w;  // inclusive local
    sdata[t] = s3;
    __syncthreads();
    for (int off = 1; off < 256; off <<= 1) {
        const int x = (t >= off) ? sdata[t - off] : 0;
        __syncthreads();
        sdata[t] += x;
        __syncthreads();
    }
    const int excl = t ? sdata[t - 1] : 0;
    int4 o; o.x = excl; o.y = excl + s0; o.z = excl + s1; o.w = excl + s2;
    *(int4*)(csr + base) = o;
    if (t == 255) bsum[blk] = sdata[255];
}

// ---------------- scan level 2: per-matrix scan of 64 block sums ----------------
__global__ void k_scan2(const int* __restrict__ bsum, int* __restrict__ bscan)
{
    const int t = threadIdx.x;      // 384 threads = 6 waves, wave w <-> matrix w
    const int lane = t & 63;
    const int orig = bsum[t];
    int v = orig;
    #pragma unroll
    for (int off = 1; off < 64; off <<= 1) {
        const int x = __shfl_up(v, off, 64);
        if (lane >= off) v += x;
    }
    bscan[t] = v - orig;            // exclusive
}

// ---------------- scan level 3: add block offsets, init cursor ----------------
__global__ __launch_bounds__(256) void k_scan3(int* __restrict__ csr,
                                               int* __restrict__ cursor,
                                               const int* __restrict__ bscan)
{
    const int blk = blockIdx.x, t = threadIdx.x;
    const int add = bscan[blk];
    const int base = blk * 1024 + t * 4;
    int4 v = *(const int4*)(csr + base);
    v.x += add; v.y += add; v.z += add; v.w += add;
    *(int4*)(csr + base) = v;
    *(int4*)(cursor + base) = v;
}

// ---------------- CSR fill ----------------
__global__ __launch_bounds__(256) void k_fill(Mats m, uint2* __restrict__ slots,
                                              int* __restrict__ cursor)
{
    const int g  = blockIdx.x * 256 + threadIdx.x;
    const int mm = g >> 20;
    const int i  = g & (NNZV - 1);
    const int row = m.rows[mm][i];
    const int pos = atomicAdd(&cursor[mm * NB + row], 1);
    slots[(size_t)mm * NNZV + pos] =
        make_uint2((unsigned)m.cols[mm][i], __float_as_uint(m.vals[mm][i]));
}

// ---------------- gather: aggY[set][row][c] = sum of val*P, both dirs ----------------
// One thread per (set,row,comp-pair): 3.1M fully independent threads,
// no atomics, no LDS, two interleaved load chains (dir 0 and dir 1).
__global__ __launch_bounds__(256) void k_gather(const uint2* __restrict__ slots,
                                                const int* __restrict__ csr,
                                                const int* __restrict__ cnt,
                                                const float* __restrict__ Pcat,
                                                float* __restrict__ aggY)
{
    const int tid = blockIdx.x * 256 + threadIdx.x;   // 3*NB*16 = 3*2^20
    const int pp  = tid & 15;
    const int row = (tid >> 4) & (NB - 1);
    const int set = tid >> 20;
    const int c2  = pp << 1;

    const int m0 = set * 2, m1 = m0 + 1;
    const int b0 = csr[m0 * NB + row], d0 = cnt[m0 * NB + row];
    const int b1 = csr[m1 * NB + row], d1 = cnt[m1 * NB + row];
    const uint2* __restrict__ s0 = slots + (size_t)m0 * NNZV + b0;
    const uint2* __restrict__ s1 = slots + (size_t)m1 * NNZV + b1;
    const float* __restrict__ P0 = Pcat + c2;
    const float* __restrict__ P1 = Pcat + (size_t)N_RELS * 32 + c2;

    float ax = 0.f, ay = 0.f, bx = 0.f, by = 0.f;
    const int dm = max(d0, d1);
    for (int j = 0; j < dm; ++j) {
        if (j < d0) {
            const uint2 e = s0[j];
            const float2 p = *reinterpret_cast<const float2*>(P0 + (e.x << 5));
            const float v = __uint_as_float(e.y);
            ax += v * p.x; ay += v * p.y;
        }
        if (j < d1) {
            const uint2 e = s1[j];
            const float2 p = *reinterpret_cast<const float2*>(P1 + (e.x << 5));
            const float v = __uint_as_float(e.y);
            bx += v * p.x; by += v * p.y;
        }
    }
    float2 r; r.x = ax + bx; r.y = ay + by;
    *reinterpret_cast<float2*>(aggY + ((size_t)set * NB + row) * 32 + c2) = r;
}

// ---------------- fallback scatter (ws too small) ----------------
__global__ void k_scatter(const int* __restrict__ rows, const int* __restrict__ cols,
                          const float* __restrict__ vals,
                          const float* __restrict__ Ptab, float* __restrict__ accs)
{
    const int stride = gridDim.x * blockDim.x;
    const int total = NNZV << 4;
    for (int g = blockIdx.x * blockDim.x + threadIdx.x; g < total; g += stride) {
        const int c2 = (g & 15) << 1;
        const int i  = g >> 4;
        const int row = rows[i];
        const int col = cols[i];
        const float v = vals[i];
        const float* p = Ptab + (col << 5) + c2;
        const int dst = (row << 5) + c2;
#if defined(__has_builtin) && __has_builtin(__builtin_amdgcn_global_atomic_fadd_v2f32)
        typedef __attribute__((address_space(1))) v2f* v2f_as1;
        v2f pv; pv.x = v * p[0]; pv.y = v * p[1];
        __builtin_amdgcn_global_atomic_fadd_v2f32(
            (v2f_as1)(unsigned long long)(accs + dst), pv);
#else
        atomicAdd(accs + dst,     v * p[0]);
        atomicAdd(accs + dst + 1, v * p[1]);
#endif
    }
}

// ---------------- GEMM: Y[set] = normalize(feat @ W.T + b' + agg) ----------------
__global__ __launch_bounds__(256) void k_gemm(
    const float* __restrict__ feat_h, const float* __restrict__ feat_p,
    const float* __restrict__ feat_n,
    const s16x8* __restrict__ wsB, const float* __restrict__ bprime,
    float* __restrict__ Y)
{
    const int lane = threadIdx.x & 63;
    const int wid  = blockIdx.x * 4 + (threadIdx.x >> 6);
    const int set  = wid >> 12;
    const int tile = wid & 4095;
    const int e0   = tile << 4;
    const float* feat = (set == 0) ? feat_h : ((set == 1) ? feat_p : feat_n);

    const int l15 = lane & 15;
    const int kq  = lane >> 4;

    const float4* ap4 = reinterpret_cast<const float4*>(
        feat + (size_t)(e0 + l15) * FEATD + (kq << 3));
    const s16x8* bp = wsB + lane;

    f32x4 acc0 = {0.f, 0.f, 0.f, 0.f};
    f32x4 acc1 = {0.f, 0.f, 0.f, 0.f};

    float4 a0 = ap4[0], a1 = ap4[1];
    #pragma unroll 4
    for (int kk = 0; kk < 24; ++kk) {
        float4 n0, n1;
        if (kk < 23) { n0 = ap4[(kk + 1) * 8]; n1 = ap4[(kk + 1) * 8 + 1]; }
        const s16x8 b0 = bp[(kk * 2 + 0) << 6];
        const s16x8 b1 = bp[(kk * 2 + 1) << 6];
        s16x8 av;
        av[0] = f2bf(a0.x); av[1] = f2bf(a0.y); av[2] = f2bf(a0.z); av[3] = f2bf(a0.w);
        av[4] = f2bf(a1.x); av[5] = f2bf(a1.y); av[6] = f2bf(a1.z); av[7] = f2bf(a1.w);
        acc0 = __builtin_amdgcn_mfma_f32_16x16x32_bf16(av, b0, acc0, 0, 0, 0);
        acc1 = __builtin_amdgcn_mfma_f32_16x16x32_bf16(av, b1, acc1, 0, 0, 0);
        a0 = n0; a1 = n1;
    }

    float* yrow = Y + (size_t)set * NB * 32;
    const float bp0 = bprime[l15], bp1 = bprime[l15 + 16];
    const int rbase = e0 + (kq << 2);
    #pragma unroll
    for (int e = 0; e < 4; ++e) {
        const int ent = rbase + e;
        float v0 = acc0[e] + bp0 + yrow[ent * 32 + l15];
        float v1 = acc1[e] + bp1 + yrow[ent * 32 + l15 + 16];
        float sq = v0 * v0 + v1 * v1;
        sq += __shfl_xor(sq, 1);
        sq += __shfl_xor(sq, 2);
        sq += __shfl_xor(sq, 4);
        sq += __shfl_xor(sq, 8);
        const float inv = 1.f / fmaxf(sqrtf(sq), 1e-12f);
        yrow[ent * 32 + l15]      = v0 * inv;
        yrow[ent * 32 + l15 + 16] = v1 * inv;
    }
}

// ---------------- scores ----------------
__global__ __launch_bounds__(256) void k_score(const float* __restrict__ Y,
                                               const int* __restrict__ eid,
                                               const float* __restrict__ Prel,
                                               float* __restrict__ out)
{
    const int tid = blockIdx.x * 256 + threadIdx.x;
    const int ent = tid >> 5;
    const int c   = tid & 31;
    const float yh = Y[((size_t)0 * NB + ent) * 32 + c];
    const float yp = Y[((size_t)1 * NB + ent) * 32 + c];
    const float yn = Y[((size_t)2 * NB + ent) * 32 + c];
    const float r  = Prel[(size_t)eid[ent] * 32 + c];
    const float dp = yh + r - yp;
    const float dn = yh + r - yn;
    float sp = dp * dp, sn = dn * dn;
    #pragma unroll
    for (int m = 1; m <= 16; m <<= 1) { sp += __shfl_xor(sp, m); sn += __shfl_xor(sn, m); }
    if (c == 0) { out[ent] = sqrtf(sp); out[NB + ent] = sqrtf(sn); }
}

extern "C" void kernel_launch(void* const* d_in, const int* in_sizes, int n_in,
                              void* d_out, int out_size, void* d_ws, size_t ws_size,
                              hipStream_t stream)
{
    const float* feat_h = (const float*)d_in[6];
    const float* feat_p = (const float*)d_in[13];
    const float* feat_n = (const float*)d_in[20];
    const int*   eid    = (const int*)d_in[21];
    const float* rel_emb = (const float*)d_in[22];
    const float* W_in  = (const float*)d_in[23];
    const float* b_in  = (const float*)d_in[24];
    const float* W_out = (const float*)d_in[25];
    const float* b_out = (const float*)d_in[26];
    const float* W_ent = (const float*)d_in[27];
    const float* b_ent = (const float*)d_in[28];
    const float* W_rel = (const float*)d_in[29];
    const float* b_rel = (const float*)d_in[30];

    char* ws = (char*)d_ws;
    const size_t AGG_B   = (size_t)3 * NB * 32 * 4;      // 25,165,824
    const size_t SLOTS_B = (size_t)6 * NNZV * 8;         // 50,331,648
    const size_t CNT_B   = (size_t)6 * NB * 4;           // 1,572,864
    const size_t CSR_B   = CNT_B;
    const size_t CUR_B   = CNT_B;
    const size_t BS_B    = 2048;                          // 384 ints, padded
    const size_t PCAT_B  = (size_t)2 * N_RELS * 32 * 4;
    const size_t PREL_B  = (size_t)N_RELS * 32 * 4;
    const size_t BPR_B   = 128;
    const size_t WSB_B   = (size_t)24 * 2 * 64 * 16;
    const bool fast = ws_size >= AGG_B + SLOTS_B + CNT_B + CSR_B + CUR_B + 2 * BS_B
                                + PCAT_B + PREL_B + BPR_B + WSB_B;

    float* aggY = (float*)ws;
    size_t off = AGG_B;
    uint2* slots = nullptr; int *cnt = nullptr, *csr = nullptr, *cur = nullptr,
          *bsum = nullptr, *bscan = nullptr;
    if (fast) {
        slots = (uint2*)(ws + off); off += SLOTS_B;
        cnt   = (int*)(ws + off);   off += CNT_B;
        csr   = (int*)(ws + off);   off += CSR_B;
        cur   = (int*)(ws + off);   off += CUR_B;
        bsum  = (int*)(ws + off);   off += BS_B;
        bscan = (int*)(ws + off);   off += BS_B;
    }
    float* Pcat   = (float*)(ws + off); off += PCAT_B;
    float* Prel   = (float*)(ws + off); off += PREL_B;
    float* bprime = (float*)(ws + off); off += BPR_B;
    s16x8* wsB    = (s16x8*)(ws + off);

    k_prep<<<(3 * N_RELS + 7) / 8, 256, 0, stream>>>(rel_emb, W_in, b_in, W_out, b_out,
                                                     W_ent, b_ent, W_rel, b_rel,
                                                     Pcat, Prel, bprime);
    k_wfrag<<<12, 256, 0, stream>>>(W_ent, wsB);

    static const int base_idx[6] = {0, 3, 7, 10, 14, 17};
    if (fast) {
        Mats m;
        for (int i = 0; i < 6; ++i) {
            m.rows[i] = (const int*)d_in[base_idx[i]];
            m.cols[i] = (const int*)d_in[base_idx[i] + 1];
            m.vals[i] = (const float*)d_in[base_idx[i] + 2];
        }
        hipMemsetAsync(cnt, 0, CNT_B, stream);
        k_count<<<6 * NNZV / 256, 256, 0, stream>>>(m, cnt);
        k_scan1<<<6 * NB / 1024, 256, 0, stream>>>(cnt, csr, bsum);
        k_scan2<<<1, 384, 0, stream>>>(bsum, bscan);
        k_scan3<<<6 * NB / 1024, 256, 0, stream>>>(csr, cur, bscan);
        k_fill<<<6 * NNZV / 256, 256, 0, stream>>>(m, slots, cur);
        k_gather<<<3 * NB * 16 / 256, 256, 0, stream>>>(slots, csr, cnt, Pcat, aggY);
    } else {
        hipMemsetAsync(aggY, 0, AGG_B, stream);
        for (int mm = 0; mm < 6; ++mm) {
            const int d = mm & 1, s = mm >> 1;
            k_scatter<<<32768, 256, 0, stream>>>((const int*)d_in[base_idx[mm]],
                                                 (const int*)d_in[base_idx[mm] + 1],
                                                 (const float*)d_in[base_idx[mm] + 2],
                                                 Pcat + (size_t)d * N_RELS * 32,
                                                 aggY + (size_t)s * NB * 32);
        }
    }

    k_gemm<<<3072, 256, 0, stream>>>(feat_h, feat_p, feat_n, wsB, bprime, aggY);
    k_score<<<8192, 256, 0, stream>>>(aggY, eid, Prel, (float*)d_out);
}

// Round 8
// 391.238 us; speedup vs baseline: 3.7701x; 2.6199x over previous
//
#include <hip/hip_runtime.h>
#include <math.h>

#define N_RELS 1315
#define NB 65536
#define NNZV (1 << 20)
#define FEATD 768

#define NBUK 256       // row buckets (256 rows each)
#define CAP  4608      // bin capacity per (matrix,bucket); mean 4096, sigma 64 -> +8 sigma
#define CHUNK 4096     // edges per k_bin block
#define STG  2048      // edges per stage
#define EPT  8         // edges per thread per stage (256 threads)
#define MAXE 18        // CAP/256 per-thread edges in k_lfill

typedef float f32x4 __attribute__((ext_vector_type(4)));
typedef short s16x8 __attribute__((ext_vector_type(8)));
typedef float v2f  __attribute__((ext_vector_type(2)));

struct Mats { const int* rows[6]; const int* cols[6]; const float* vals[6]; };

__device__ __forceinline__ short f2bf(float f) {
    return __builtin_bit_cast(short, (__bf16)f);
}

// ---------------- precompute: P tables, Prel, b' ----------------
__global__ void k_prep(const float* __restrict__ rel_emb,
                       const float* __restrict__ W_in, const float* __restrict__ b_in,
                       const float* __restrict__ W_out, const float* __restrict__ b_out,
                       const float* __restrict__ W_ent, const float* __restrict__ b_ent,
                       const float* __restrict__ W_rel, const float* __restrict__ b_rel,
                       float* __restrict__ Pcat, float* __restrict__ Prel,
                       float* __restrict__ bprime)
{
    __shared__ float C[2][32][33];
    const int tid = threadIdx.x;
    for (int idx = tid; idx < 2 * 32 * 32; idx += 256) {
        int d = idx >> 10, o = (idx >> 5) & 31, t = idx & 31;
        const float* W  = d ? W_out : W_in;
        const float* we = W_ent + o * 832 + 768 + d * 32;
        float s = 0.f;
        #pragma unroll
        for (int j = 0; j < 32; ++j) s += we[j] * W[j * 32 + t];
        C[d][o][t] = s;
    }
    __syncthreads();

    const int row8 = blockIdx.x * 8 + (tid >> 5);
    const int o = tid & 31;
    if (row8 < 2 * N_RELS) {
        const int d = (row8 >= N_RELS) ? 1 : 0;
        const int r = row8 - d * N_RELS;
        const float* re = rel_emb + r * 32;
        float s = 0.f;
        #pragma unroll
        for (int t = 0; t < 32; ++t) s += re[t] * C[d][o][t];
        Pcat[row8 * 32 + o] = s;
    } else if (row8 < 3 * N_RELS) {
        const int r = row8 - 2 * N_RELS;
        const float* re = rel_emb + r * 32;
        float s = b_rel[o];
        #pragma unroll
        for (int j = 0; j < 32; ++j) s += W_rel[o * 32 + j] * re[j];
        float sq = s * s;
        #pragma unroll
        for (int m = 16; m; m >>= 1) sq += __shfl_xor(sq, m);
        Prel[r * 32 + o] = s / fmaxf(sqrtf(sq), 1e-12f);
    }
    if (blockIdx.x == 0 && tid < 32) {
        float s = b_ent[tid];
        #pragma unroll
        for (int j = 0; j < 32; ++j)
            s += b_in[j] * W_ent[tid * 832 + 768 + j] + b_out[j] * W_ent[tid * 832 + 800 + j];
        bprime[tid] = s;
    }
}

// ---------------- pack W_ent[:, :768] into bf16 B-fragments ----------------
__global__ void k_wfrag(const float* __restrict__ W_ent, s16x8* __restrict__ wsB)
{
    const int t = blockIdx.x * 256 + threadIdx.x;
    if (t >= 24 * 2 * 64) return;
    const int kk = t >> 7, rem = t & 127, nt = rem >> 6, l = rem & 63;
    const int col = nt * 16 + (l & 15);
    const int k0  = kk * 32 + ((l >> 4) << 3);
    const float* w = W_ent + col * 832 + k0;
    s16x8 v;
    #pragma unroll
    for (int e = 0; e < 8; ++e) v[e] = f2bf(w[e]);
    wsB[t] = v;
}

// ---------------- cursor init ----------------
__global__ void k_cursor(unsigned* __restrict__ cursor)
{
    const int i = blockIdx.x * 256 + threadIdx.x;
    if (i < 6 * NBUK) cursor[i] = (unsigned)i * CAP;
}

// ---------------- bin edges by row bucket (proven ~60us) ----------------
__global__ __launch_bounds__(256) void k_bin(Mats m, uint2* __restrict__ bins,
                                             unsigned* __restrict__ cursor)
{
    __shared__ unsigned lcnt[NBUK];
    __shared__ unsigned gbase[NBUK];
    const int mm    = blockIdx.x >> 8;      // 6 matrices x 256 chunks
    const int chunk = blockIdx.x & 255;
    const int tid   = threadIdx.x;
    const int* __restrict__ R = m.rows[mm];
    const int* __restrict__ C = m.cols[mm];
    const float* __restrict__ V = m.vals[mm];
    const int base = chunk * CHUNK;

    for (int st = 0; st < CHUNK / STG; ++st) {
        for (int i = tid; i < NBUK; i += 256) lcnt[i] = 0;
        __syncthreads();
        unsigned meta[EPT]; float val[EPT]; unsigned short lrank[EPT]; unsigned char buk[EPT];
        #pragma unroll
        for (int e = 0; e < EPT; ++e) {
            const int idx = base + st * STG + e * 256 + tid;
            const int row = R[idx];
            const int col = C[idx];
            val[e]  = V[idx];
            buk[e]  = (unsigned char)(row >> 8);
            meta[e] = ((unsigned)(row & 255) << 11) | (unsigned)col;
            lrank[e] = (unsigned short)atomicAdd(&lcnt[buk[e]], 1u);
        }
        __syncthreads();
        gbase[tid] = atomicAdd(&cursor[mm * NBUK + tid], lcnt[tid]);
        __syncthreads();
        #pragma unroll
        for (int e = 0; e < EPT; ++e)
            bins[gbase[buk[e]] + lrank[e]] = make_uint2(meta[e], __float_as_uint(val[e]));
        __syncthreads();
    }
}

// ---------------- bucket-local CSR fill (in-place, line-local writes) ----------------
// One block per (matrix,bucket). Edges -> registers (fixed-trip unroll),
// LDS histogram + scan of 256 local rows, coalesced csr/cnt out, then
// in-place permutation write inside the 36KB segment (L2 write-combines).
__global__ __launch_bounds__(256) void k_lfill(uint2* __restrict__ bins,
                                               const unsigned* __restrict__ cursor,
                                               int* __restrict__ csr,
                                               int* __restrict__ cnt)
{
    __shared__ int hist[256];
    __shared__ int sc[256];
    __shared__ int ofs[256];
    const int mb = blockIdx.x;                 // mm*NBUK + b
    const unsigned segbase = (unsigned)mb * CAP;
    uint2* __restrict__ seg = bins + segbase;
    const int len = (int)(cursor[mb] - segbase);
    const int t = threadIdx.x;

    hist[t] = 0;
    __syncthreads();

    uint2 e[MAXE];
    #pragma unroll
    for (int j = 0; j < MAXE; ++j) {
        const int i = t + j * 256;
        if (i < len) e[j] = seg[i];
    }
    #pragma unroll
    for (int j = 0; j < MAXE; ++j) {
        const int i = t + j * 256;
        if (i < len) atomicAdd(&hist[e[j].x >> 11], 1);
    }
    __syncthreads();          // also drains all seg reads (vmcnt before barrier)

    sc[t] = hist[t];
    __syncthreads();
    for (int off = 1; off < 256; off <<= 1) {
        const int x = (t >= off) ? sc[t - off] : 0;
        __syncthreads();
        sc[t] += x;
        __syncthreads();
    }
    const int excl = t ? sc[t - 1] : 0;
    ofs[t] = excl;
    const int mm = mb >> 8, b = mb & 255;
    csr[mm * NB + b * 256 + t] = (int)segbase + excl;
    cnt[mm * NB + b * 256 + t] = hist[t];
    __syncthreads();

    #pragma unroll
    for (int j = 0; j < MAXE; ++j) {
        const int i = t + j * 256;
        if (i < len) {
            const int pos = atomicAdd(&ofs[e[j].x >> 11], 1);
            seg[pos] = make_uint2(e[j].x & 2047u, e[j].y);
        }
    }
}

// ---------------- gather: aggY[set][row][c] = sum of val*P, both dirs ----------------
__global__ __launch_bounds__(256) void k_gather(const uint2* __restrict__ slots,
                                                const int* __restrict__ csr,
                                                const int* __restrict__ cnt,
                                                const float* __restrict__ Pcat,
                                                float* __restrict__ aggY)
{
    const int tid = blockIdx.x * 256 + threadIdx.x;   // 3*NB*16 = 3*2^20
    const int pp  = tid & 15;
    const int row = (tid >> 4) & (NB - 1);
    const int set = tid >> 20;
    const int c2  = pp << 1;

    const int m0 = set * 2, m1 = m0 + 1;
    const int b0 = csr[m0 * NB + row], d0 = cnt[m0 * NB + row];
    const int b1 = csr[m1 * NB + row], d1 = cnt[m1 * NB + row];
    const uint2* __restrict__ s0 = slots + b0;
    const uint2* __restrict__ s1 = slots + b1;
    const float* __restrict__ P0 = Pcat + c2;
    const float* __restrict__ P1 = Pcat + (size_t)N_RELS * 32 + c2;

    float ax = 0.f, ay = 0.f, bx = 0.f, by = 0.f;
    const int dm = max(d0, d1);
    for (int j = 0; j < dm; ++j) {
        if (j < d0) {
            const uint2 e = s0[j];
            const float2 p = *reinterpret_cast<const float2*>(P0 + (e.x << 5));
            const float v = __uint_as_float(e.y);
            ax += v * p.x; ay += v * p.y;
        }
        if (j < d1) {
            const uint2 e = s1[j];
            const float2 p = *reinterpret_cast<const float2*>(P1 + (e.x << 5));
            const float v = __uint_as_float(e.y);
            bx += v * p.x; by += v * p.y;
        }
    }
    float2 r; r.x = ax + bx; r.y = ay + by;
    *reinterpret_cast<float2*>(aggY + ((size_t)set * NB + row) * 32 + c2) = r;
}

// ---------------- fallback scatter (ws too small) ----------------
__global__ void k_scatter(const int* __restrict__ rows, const int* __restrict__ cols,
                          const float* __restrict__ vals,
                          const float* __restrict__ Ptab, float* __restrict__ accs)
{
    const int stride = gridDim.x * blockDim.x;
    const int total = NNZV << 4;
    for (int g = blockIdx.x * blockDim.x + threadIdx.x; g < total; g += stride) {
        const int c2 = (g & 15) << 1;
        const int i  = g >> 4;
        const int row = rows[i];
        const int col = cols[i];
        const float v = vals[i];
        const float* p = Ptab + (col << 5) + c2;
        const int dst = (row << 5) + c2;
#if defined(__has_builtin) && __has_builtin(__builtin_amdgcn_global_atomic_fadd_v2f32)
        typedef __attribute__((address_space(1))) v2f* v2f_as1;
        v2f pv; pv.x = v * p[0]; pv.y = v * p[1];
        __builtin_amdgcn_global_atomic_fadd_v2f32(
            (v2f_as1)(unsigned long long)(accs + dst), pv);
#else
        atomicAdd(accs + dst,     v * p[0]);
        atomicAdd(accs + dst + 1, v * p[1]);
#endif
    }
}

// ---------------- GEMM: Y[set] = normalize(feat @ W.T + b' + agg) ----------------
__global__ __launch_bounds__(256) void k_gemm(
    const float* __restrict__ feat_h, const float* __restrict__ feat_p,
    const float* __restrict__ feat_n,
    const s16x8* __restrict__ wsB, const float* __restrict__ bprime,
    float* __restrict__ Y)
{
    const int lane = threadIdx.x & 63;
    const int wid  = blockIdx.x * 4 + (threadIdx.x >> 6);
    const int set  = wid >> 12;
    const int tile = wid & 4095;
    const int e0   = tile << 4;
    const float* feat = (set == 0) ? feat_h : ((set == 1) ? feat_p : feat_n);

    const int l15 = lane & 15;
    const int kq  = lane >> 4;

    const float4* ap4 = reinterpret_cast<const float4*>(
        feat + (size_t)(e0 + l15) * FEATD + (kq << 3));
    const s16x8* bp = wsB + lane;

    f32x4 acc0 = {0.f, 0.f, 0.f, 0.f};
    f32x4 acc1 = {0.f, 0.f, 0.f, 0.f};

    float4 a0 = ap4[0], a1 = ap4[1];
    #pragma unroll 4
    for (int kk = 0; kk < 24; ++kk) {
        float4 n0, n1;
        if (kk < 23) { n0 = ap4[(kk + 1) * 8]; n1 = ap4[(kk + 1) * 8 + 1]; }
        const s16x8 b0 = bp[(kk * 2 + 0) << 6];
        const s16x8 b1 = bp[(kk * 2 + 1) << 6];
        s16x8 av;
        av[0] = f2bf(a0.x); av[1] = f2bf(a0.y); av[2] = f2bf(a0.z); av[3] = f2bf(a0.w);
        av[4] = f2bf(a1.x); av[5] = f2bf(a1.y); av[6] = f2bf(a1.z); av[7] = f2bf(a1.w);
        acc0 = __builtin_amdgcn_mfma_f32_16x16x32_bf16(av, b0, acc0, 0, 0, 0);
        acc1 = __builtin_amdgcn_mfma_f32_16x16x32_bf16(av, b1, acc1, 0, 0, 0);
        a0 = n0; a1 = n1;
    }

    float* yrow = Y + (size_t)set * NB * 32;
    const float bp0 = bprime[l15], bp1 = bprime[l15 + 16];
    const int rbase = e0 + (kq << 2);
    #pragma unroll
    for (int e = 0; e < 4; ++e) {
        const int ent = rbase + e;
        float v0 = acc0[e] + bp0 + yrow[ent * 32 + l15];
        float v1 = acc1[e] + bp1 + yrow[ent * 32 + l15 + 16];
        float sq = v0 * v0 + v1 * v1;
        sq += __shfl_xor(sq, 1);
        sq += __shfl_xor(sq, 2);
        sq += __shfl_xor(sq, 4);
        sq += __shfl_xor(sq, 8);
        const float inv = 1.f / fmaxf(sqrtf(sq), 1e-12f);
        yrow[ent * 32 + l15]      = v0 * inv;
        yrow[ent * 32 + l15 + 16] = v1 * inv;
    }
}

// ---------------- scores ----------------
__global__ __launch_bounds__(256) void k_score(const float* __restrict__ Y,
                                               const int* __restrict__ eid,
                                               const float* __restrict__ Prel,
                                               float* __restrict__ out)
{
    const int tid = blockIdx.x * 256 + threadIdx.x;
    const int ent = tid >> 5;
    const int c   = tid & 31;
    const float yh = Y[((size_t)0 * NB + ent) * 32 + c];
    const float yp = Y[((size_t)1 * NB + ent) * 32 + c];
    const float yn = Y[((size_t)2 * NB + ent) * 32 + c];
    const float r  = Prel[(size_t)eid[ent] * 32 + c];
    const float dp = yh + r - yp;
    const float dn = yh + r - yn;
    float sp = dp * dp, sn = dn * dn;
    #pragma unroll
    for (int m = 1; m <= 16; m <<= 1) { sp += __shfl_xor(sp, m); sn += __shfl_xor(sn, m); }
    if (c == 0) { out[ent] = sqrtf(sp); out[NB + ent] = sqrtf(sn); }
}

extern "C" void kernel_launch(void* const* d_in, const int* in_sizes, int n_in,
                              void* d_out, int out_size, void* d_ws, size_t ws_size,
                              hipStream_t stream)
{
    const float* feat_h = (const float*)d_in[6];
    const float* feat_p = (const float*)d_in[13];
    const float* feat_n = (const float*)d_in[20];
    const int*   eid    = (const int*)d_in[21];
    const float* rel_emb = (const float*)d_in[22];
    const float* W_in  = (const float*)d_in[23];
    const float* b_in  = (const float*)d_in[24];
    const float* W_out = (const float*)d_in[25];
    const float* b_out = (const float*)d_in[26];
    const float* W_ent = (const float*)d_in[27];
    const float* b_ent = (const float*)d_in[28];
    const float* W_rel = (const float*)d_in[29];
    const float* b_rel = (const float*)d_in[30];

    char* ws = (char*)d_ws;
    const size_t AGG_B   = (size_t)3 * NB * 32 * 4;          // 25,165,824
    const size_t BINS_B  = (size_t)6 * NBUK * CAP * 8;       // 56,623,104
    const size_t CURS_B  = 8192;
    const size_t CSR_B   = (size_t)6 * NB * 4;               // 1,572,864
    const size_t CNT_B   = CSR_B;
    const size_t PCAT_B  = (size_t)2 * N_RELS * 32 * 4;
    const size_t PREL_B  = (size_t)N_RELS * 32 * 4;
    const size_t BPR_B   = 128;
    const size_t WSB_B   = (size_t)24 * 2 * 64 * 16;
    const bool fast = ws_size >= AGG_B + BINS_B + CURS_B + CSR_B + CNT_B
                                + PCAT_B + PREL_B + BPR_B + WSB_B;

    float* aggY = (float*)ws;
    size_t off = AGG_B;
    uint2* bins = nullptr; unsigned* cursor = nullptr; int *csr = nullptr, *cnt = nullptr;
    if (fast) {
        bins   = (uint2*)(ws + off);    off += BINS_B;
        cursor = (unsigned*)(ws + off); off += CURS_B;
        csr    = (int*)(ws + off);      off += CSR_B;
        cnt    = (int*)(ws + off);      off += CNT_B;
    }
    float* Pcat   = (float*)(ws + off); off += PCAT_B;
    float* Prel   = (float*)(ws + off); off += PREL_B;
    float* bprime = (float*)(ws + off); off += BPR_B;
    s16x8* wsB    = (s16x8*)(ws + off);

    k_prep<<<(3 * N_RELS + 7) / 8, 256, 0, stream>>>(rel_emb, W_in, b_in, W_out, b_out,
                                                     W_ent, b_ent, W_rel, b_rel,
                                                     Pcat, Prel, bprime);
    k_wfrag<<<12, 256, 0, stream>>>(W_ent, wsB);

    static const int base_idx[6] = {0, 3, 7, 10, 14, 17};
    if (fast) {
        Mats m;
        for (int i = 0; i < 6; ++i) {
            m.rows[i] = (const int*)d_in[base_idx[i]];
            m.cols[i] = (const int*)d_in[base_idx[i] + 1];
            m.vals[i] = (const float*)d_in[base_idx[i] + 2];
        }
        k_cursor<<<6, 256, 0, stream>>>(cursor);
        k_bin<<<6 * 256, 256, 0, stream>>>(m, bins, cursor);
        k_lfill<<<6 * NBUK, 256, 0, stream>>>(bins, cursor, csr, cnt);
        k_gather<<<3 * NB * 16 / 256, 256, 0, stream>>>(bins, csr, cnt, Pcat, aggY);
    } else {
        hipMemsetAsync(aggY, 0, AGG_B, stream);
        for (int mm = 0; mm < 6; ++mm) {
            const int d = mm & 1, s = mm >> 1;
            k_scatter<<<32768, 256, 0, stream>>>((const int*)d_in[base_idx[mm]],
                                                 (const int*)d_in[base_idx[mm] + 1],
                                                 (const float*)d_in[base_idx[mm] + 2],
                                                 Pcat + (size_t)d * N_RELS * 32,
                                                 aggY + (size_t)s * NB * 32);
        }
    }

    k_gemm<<<3072, 256, 0, stream>>>(feat_h, feat_p, feat_n, wsB, bprime, aggY);
    k_score<<<8192, 256, 0, stream>>>(aggY, eid, Prel, (float*)d_out);
}

// Round 9
// 375.240 us; speedup vs baseline: 3.9309x; 1.0426x over previous
//
#include <hip/hip_runtime.h>
#include <math.h>

#define N_RELS 1315
#define NB 65536
#define NNZV (1 << 20)
#define FEATD 768

#define NBUK 256       // row buckets (256 rows each)
#define CAP  4608      // bin capacity per (matrix,bucket); mean 4096, sigma 64 -> +8 sigma
#define CHUNK 4096     // edges per k_bin block
#define STG  2048      // edges per stage
#define EPT  8         // edges per thread per stage (256 threads)
#define MAXE 18        // CAP/256 per-thread edges in k_lfill

typedef float f32x4 __attribute__((ext_vector_type(4)));
typedef short s16x8 __attribute__((ext_vector_type(8)));
typedef float v2f  __attribute__((ext_vector_type(2)));

struct Mats { const int* rows[6]; const int* cols[6]; const float* vals[6]; };

__device__ __forceinline__ short f2bf(float f) {
    return __builtin_bit_cast(short, (__bf16)f);
}

// ---------------- precompute: P tables, Prel, b' ----------------
__global__ void k_prep(const float* __restrict__ rel_emb,
                       const float* __restrict__ W_in, const float* __restrict__ b_in,
                       const float* __restrict__ W_out, const float* __restrict__ b_out,
                       const float* __restrict__ W_ent, const float* __restrict__ b_ent,
                       const float* __restrict__ W_rel, const float* __restrict__ b_rel,
                       float* __restrict__ Pcat, float* __restrict__ Prel,
                       float* __restrict__ bprime)
{
    __shared__ float C[2][32][33];
    const int tid = threadIdx.x;
    for (int idx = tid; idx < 2 * 32 * 32; idx += 256) {
        int d = idx >> 10, o = (idx >> 5) & 31, t = idx & 31;
        const float* W  = d ? W_out : W_in;
        const float* we = W_ent + o * 832 + 768 + d * 32;
        float s = 0.f;
        #pragma unroll
        for (int j = 0; j < 32; ++j) s += we[j] * W[j * 32 + t];
        C[d][o][t] = s;
    }
    __syncthreads();

    const int row8 = blockIdx.x * 8 + (tid >> 5);
    const int o = tid & 31;
    if (row8 < 2 * N_RELS) {
        const int d = (row8 >= N_RELS) ? 1 : 0;
        const int r = row8 - d * N_RELS;
        const float* re = rel_emb + r * 32;
        float s = 0.f;
        #pragma unroll
        for (int t = 0; t < 32; ++t) s += re[t] * C[d][o][t];
        Pcat[row8 * 32 + o] = s;
    } else if (row8 < 3 * N_RELS) {
        const int r = row8 - 2 * N_RELS;
        const float* re = rel_emb + r * 32;
        float s = b_rel[o];
        #pragma unroll
        for (int j = 0; j < 32; ++j) s += W_rel[o * 32 + j] * re[j];
        float sq = s * s;
        #pragma unroll
        for (int m = 16; m; m >>= 1) sq += __shfl_xor(sq, m);
        Prel[r * 32 + o] = s / fmaxf(sqrtf(sq), 1e-12f);
    }
    if (blockIdx.x == 0 && tid < 32) {
        float s = b_ent[tid];
        #pragma unroll
        for (int j = 0; j < 32; ++j)
            s += b_in[j] * W_ent[tid * 832 + 768 + j] + b_out[j] * W_ent[tid * 832 + 800 + j];
        bprime[tid] = s;
    }
}

// ---------------- pack W_ent[:, :768] into bf16 B-fragments ----------------
__global__ void k_wfrag(const float* __restrict__ W_ent, s16x8* __restrict__ wsB)
{
    const int t = blockIdx.x * 256 + threadIdx.x;
    if (t >= 24 * 2 * 64) return;
    const int kk = t >> 7, rem = t & 127, nt = rem >> 6, l = rem & 63;
    const int col = nt * 16 + (l & 15);
    const int k0  = kk * 32 + ((l >> 4) << 3);
    const float* w = W_ent + col * 832 + k0;
    s16x8 v;
    #pragma unroll
    for (int e = 0; e < 8; ++e) v[e] = f2bf(w[e]);
    wsB[t] = v;
}

// ---------------- cursor init ----------------
__global__ void k_cursor(unsigned* __restrict__ cursor)
{
    const int i = blockIdx.x * 256 + threadIdx.x;
    if (i < 6 * NBUK) cursor[i] = (unsigned)i * CAP;
}

// ---------------- bin edges by row bucket ----------------
__global__ __launch_bounds__(256) void k_bin(Mats m, uint2* __restrict__ bins,
                                             unsigned* __restrict__ cursor)
{
    __shared__ unsigned lcnt[NBUK];
    __shared__ unsigned gbase[NBUK];
    const int mm    = blockIdx.x >> 8;      // 6 matrices x 256 chunks
    const int chunk = blockIdx.x & 255;
    const int tid   = threadIdx.x;
    const int* __restrict__ R = m.rows[mm];
    const int* __restrict__ C = m.cols[mm];
    const float* __restrict__ V = m.vals[mm];
    const int base = chunk * CHUNK;

    for (int st = 0; st < CHUNK / STG; ++st) {
        for (int i = tid; i < NBUK; i += 256) lcnt[i] = 0;
        __syncthreads();
        unsigned meta[EPT]; float val[EPT]; unsigned short lrank[EPT]; unsigned char buk[EPT];
        #pragma unroll
        for (int e = 0; e < EPT; ++e) {
            const int idx = base + st * STG + e * 256 + tid;
            const int row = R[idx];
            const int col = C[idx];
            val[e]  = V[idx];
            buk[e]  = (unsigned char)(row >> 8);
            meta[e] = ((unsigned)(row & 255) << 11) | (unsigned)col;
            lrank[e] = (unsigned short)atomicAdd(&lcnt[buk[e]], 1u);
        }
        __syncthreads();
        gbase[tid] = atomicAdd(&cursor[mm * NBUK + tid], lcnt[tid]);
        __syncthreads();
        #pragma unroll
        for (int e = 0; e < EPT; ++e)
            bins[gbase[buk[e]] + lrank[e]] = make_uint2(meta[e], __float_as_uint(val[e]));
        __syncthreads();
    }
}

// ---------------- bucket-local CSR fill (in-place, line-local writes) ----------------
__global__ __launch_bounds__(256) void k_lfill(uint2* __restrict__ bins,
                                               const unsigned* __restrict__ cursor,
                                               int* __restrict__ csr,
                                               int* __restrict__ cnt)
{
    __shared__ int hist[256];
    __shared__ int sc[256];
    __shared__ int ofs[256];
    const int mb = blockIdx.x;                 // mm*NBUK + b
    const unsigned segbase = (unsigned)mb * CAP;
    uint2* __restrict__ seg = bins + segbase;
    const int len = (int)(cursor[mb] - segbase);
    const int t = threadIdx.x;

    hist[t] = 0;
    __syncthreads();

    uint2 e[MAXE];
    #pragma unroll
    for (int j = 0; j < MAXE; ++j) {
        const int i = t + j * 256;
        if (i < len) e[j] = seg[i];
    }
    #pragma unroll
    for (int j = 0; j < MAXE; ++j) {
        const int i = t + j * 256;
        if (i < len) atomicAdd(&hist[e[j].x >> 11], 1);
    }
    __syncthreads();          // also drains all seg reads (vmcnt before barrier)

    sc[t] = hist[t];
    __syncthreads();
    for (int off = 1; off < 256; off <<= 1) {
        const int x = (t >= off) ? sc[t - off] : 0;
        __syncthreads();
        sc[t] += x;
        __syncthreads();
    }
    const int excl = t ? sc[t - 1] : 0;
    ofs[t] = excl;
    const int mm = mb >> 8, b = mb & 255;
    csr[mm * NB + b * 256 + t] = (int)segbase + excl;
    cnt[mm * NB + b * 256 + t] = hist[t];
    __syncthreads();

    #pragma unroll
    for (int j = 0; j < MAXE; ++j) {
        const int i = t + j * 256;
        if (i < len) {
            const int pos = atomicAdd(&ofs[e[j].x >> 11], 1);
            seg[pos] = make_uint2(e[j].x & 2047u, e[j].y);
        }
    }
}

// ---------------- gather: aggY[set][row][c] = sum of val*P, both dirs ----------------
// 2-edge batching per direction: 4 independent edge loads then 4 independent
// P loads in flight per iteration. Zero-val padding makes tails no-ops.
__global__ __launch_bounds__(256) void k_gather(const uint2* __restrict__ slots,
                                                const int* __restrict__ csr,
                                                const int* __restrict__ cnt,
                                                const float* __restrict__ Pcat,
                                                float* __restrict__ aggY)
{
    const int tid = blockIdx.x * 256 + threadIdx.x;   // 3*NB*16 = 3*2^20
    const int pp  = tid & 15;
    const int row = (tid >> 4) & (NB - 1);
    const int set = tid >> 20;
    const int c2  = pp << 1;

    const int m0 = set * 2, m1 = m0 + 1;
    const int b0 = csr[m0 * NB + row], d0 = cnt[m0 * NB + row];
    const int b1 = csr[m1 * NB + row], d1 = cnt[m1 * NB + row];
    const uint2* __restrict__ s0 = slots + b0;
    const uint2* __restrict__ s1 = slots + b1;
    const float* __restrict__ P0 = Pcat + c2;
    const float* __restrict__ P1 = Pcat + (size_t)N_RELS * 32 + c2;

    float ax = 0.f, ay = 0.f, bx = 0.f, by = 0.f;
    const int dm = max(d0, d1);
    for (int j = 0; j < dm; j += 2) {
        uint2 ea0 = make_uint2(0u, 0u), ea1 = ea0, eb0 = ea0, eb1 = ea0;
        if (j     < d0) ea0 = s0[j];
        if (j + 1 < d0) ea1 = s0[j + 1];
        if (j     < d1) eb0 = s1[j];
        if (j + 1 < d1) eb1 = s1[j + 1];
        const float2 pa0 = *reinterpret_cast<const float2*>(P0 + (ea0.x << 5));
        const float2 pa1 = *reinterpret_cast<const float2*>(P0 + (ea1.x << 5));
        const float2 pb0 = *reinterpret_cast<const float2*>(P1 + (eb0.x << 5));
        const float2 pb1 = *reinterpret_cast<const float2*>(P1 + (eb1.x << 5));
        const float va0 = __uint_as_float(ea0.y), va1 = __uint_as_float(ea1.y);
        const float vb0 = __uint_as_float(eb0.y), vb1 = __uint_as_float(eb1.y);
        ax += va0 * pa0.x + va1 * pa1.x;  ay += va0 * pa0.y + va1 * pa1.y;
        bx += vb0 * pb0.x + vb1 * pb1.x;  by += vb0 * pb0.y + vb1 * pb1.y;
    }
    float2 r; r.x = ax + bx; r.y = ay + by;
    *reinterpret_cast<float2*>(aggY + ((size_t)set * NB + row) * 32 + c2) = r;
}

// ---------------- fallback scatter (ws too small) ----------------
__global__ void k_scatter(const int* __restrict__ rows, const int* __restrict__ cols,
                          const float* __restrict__ vals,
                          const float* __restrict__ Ptab, float* __restrict__ accs)
{
    const int stride = gridDim.x * blockDim.x;
    const int total = NNZV << 4;
    for (int g = blockIdx.x * blockDim.x + threadIdx.x; g < total; g += stride) {
        const int c2 = (g & 15) << 1;
        const int i  = g >> 4;
        const int row = rows[i];
        const int col = cols[i];
        const float v = vals[i];
        const float* p = Ptab + (col << 5) + c2;
        const int dst = (row << 5) + c2;
#if defined(__has_builtin) && __has_builtin(__builtin_amdgcn_global_atomic_fadd_v2f32)
        typedef __attribute__((address_space(1))) v2f* v2f_as1;
        v2f pv; pv.x = v * p[0]; pv.y = v * p[1];
        __builtin_amdgcn_global_atomic_fadd_v2f32(
            (v2f_as1)(unsigned long long)(accs + dst), pv);
#else
        atomicAdd(accs + dst,     v * p[0]);
        atomicAdd(accs + dst + 1, v * p[1]);
#endif
    }
}

// ---------------- GEMM v2: 32-entity tiles per wave, prefetched A ----------------
// Y[set] = normalize(feat @ W.T + b' + agg), in-place over aggY.
__global__ __launch_bounds__(256) void k_gemm(
    const float* __restrict__ feat_h, const float* __restrict__ feat_p,
    const float* __restrict__ feat_n,
    const s16x8* __restrict__ wsB, const float* __restrict__ bprime,
    float* __restrict__ Y)
{
    const int lane = threadIdx.x & 63;
    const int wid  = blockIdx.x * 4 + (threadIdx.x >> 6);   // 0..6143
    const int set  = wid >> 11;                             // 2048 tiles/set
    const int tile = wid & 2047;
    const int e0   = tile << 5;                             // 32 entities
    const float* feat = (set == 0) ? feat_h : ((set == 1) ? feat_p : feat_n);

    const int l15 = lane & 15;
    const int kq  = lane >> 4;

    const float4* ap0 = reinterpret_cast<const float4*>(
        feat + (size_t)(e0 + l15) * FEATD + (kq << 3));
    const float4* ap1 = reinterpret_cast<const float4*>(
        feat + (size_t)(e0 + 16 + l15) * FEATD + (kq << 3));
    const s16x8* bp = wsB + lane;

    f32x4 acc00 = {0.f, 0.f, 0.f, 0.f};
    f32x4 acc01 = {0.f, 0.f, 0.f, 0.f};
    f32x4 acc10 = {0.f, 0.f, 0.f, 0.f};
    f32x4 acc11 = {0.f, 0.f, 0.f, 0.f};

    float4 a00 = ap0[0], a01 = ap0[1];
    float4 a10 = ap1[0], a11 = ap1[1];
    #pragma unroll 2
    for (int kk = 0; kk < 24; ++kk) {
        float4 n00, n01, n10, n11;
        if (kk < 23) {
            n00 = ap0[(kk + 1) * 8]; n01 = ap0[(kk + 1) * 8 + 1];
            n10 = ap1[(kk + 1) * 8]; n11 = ap1[(kk + 1) * 8 + 1];
        }
        const s16x8 b0 = bp[(kk * 2 + 0) << 6];
        const s16x8 b1 = bp[(kk * 2 + 1) << 6];
        s16x8 av0, av1;
        av0[0] = f2bf(a00.x); av0[1] = f2bf(a00.y); av0[2] = f2bf(a00.z); av0[3] = f2bf(a00.w);
        av0[4] = f2bf(a01.x); av0[5] = f2bf(a01.y); av0[6] = f2bf(a01.z); av0[7] = f2bf(a01.w);
        av1[0] = f2bf(a10.x); av1[1] = f2bf(a10.y); av1[2] = f2bf(a10.z); av1[3] = f2bf(a10.w);
        av1[4] = f2bf(a11.x); av1[5] = f2bf(a11.y); av1[6] = f2bf(a11.z); av1[7] = f2bf(a11.w);
        acc00 = __builtin_amdgcn_mfma_f32_16x16x32_bf16(av0, b0, acc00, 0, 0, 0);
        acc01 = __builtin_amdgcn_mfma_f32_16x16x32_bf16(av0, b1, acc01, 0, 0, 0);
        acc10 = __builtin_amdgcn_mfma_f32_16x16x32_bf16(av1, b0, acc10, 0, 0, 0);
        acc11 = __builtin_amdgcn_mfma_f32_16x16x32_bf16(av1, b1, acc11, 0, 0, 0);
        a00 = n00; a01 = n01; a10 = n10; a11 = n11;
    }

    float* yrow = Y + (size_t)set * NB * 32;
    const float bp0 = bprime[l15], bp1 = bprime[l15 + 16];
    #pragma unroll
    for (int half = 0; half < 2; ++half) {
        const f32x4 accA = half ? acc10 : acc00;
        const f32x4 accB = half ? acc11 : acc01;
        const int rbase = e0 + half * 16 + (kq << 2);
        #pragma unroll
        for (int e = 0; e < 4; ++e) {
            const int ent = rbase + e;
            float v0 = accA[e] + bp0 + yrow[ent * 32 + l15];
            float v1 = accB[e] + bp1 + yrow[ent * 32 + l15 + 16];
            float sq = v0 * v0 + v1 * v1;
            sq += __shfl_xor(sq, 1);
            sq += __shfl_xor(sq, 2);
            sq += __shfl_xor(sq, 4);
            sq += __shfl_xor(sq, 8);
            const float inv = 1.f / fmaxf(sqrtf(sq), 1e-12f);
            yrow[ent * 32 + l15]      = v0 * inv;
            yrow[ent * 32 + l15 + 16] = v1 * inv;
        }
    }
}

// ---------------- scores ----------------
__global__ __launch_bounds__(256) void k_score(const float* __restrict__ Y,
                                               const int* __restrict__ eid,
                                               const float* __restrict__ Prel,
                                               float* __restrict__ out)
{
    const int tid = blockIdx.x * 256 + threadIdx.x;
    const int ent = tid >> 5;
    const int c   = tid & 31;
    const float yh = Y[((size_t)0 * NB + ent) * 32 + c];
    const float yp = Y[((size_t)1 * NB + ent) * 32 + c];
    const float yn = Y[((size_t)2 * NB + ent) * 32 + c];
    const float r  = Prel[(size_t)eid[ent] * 32 + c];
    const float dp = yh + r - yp;
    const float dn = yh + r - yn;
    float sp = dp * dp, sn = dn * dn;
    #pragma unroll
    for (int m = 1; m <= 16; m <<= 1) { sp += __shfl_xor(sp, m); sn += __shfl_xor(sn, m); }
    if (c == 0) { out[ent] = sqrtf(sp); out[NB + ent] = sqrtf(sn); }
}

extern "C" void kernel_launch(void* const* d_in, const int* in_sizes, int n_in,
                              void* d_out, int out_size, void* d_ws, size_t ws_size,
                              hipStream_t stream)
{
    const float* feat_h = (const float*)d_in[6];
    const float* feat_p = (const float*)d_in[13];
    const float* feat_n = (const float*)d_in[20];
    const int*   eid    = (const int*)d_in[21];
    const float* rel_emb = (const float*)d_in[22];
    const float* W_in  = (const float*)d_in[23];
    const float* b_in  = (const float*)d_in[24];
    const float* W_out = (const float*)d_in[25];
    const float* b_out = (const float*)d_in[26];
    const float* W_ent = (const float*)d_in[27];
    const float* b_ent = (const float*)d_in[28];
    const float* W_rel = (const float*)d_in[29];
    const float* b_rel = (const float*)d_in[30];

    char* ws = (char*)d_ws;
    const size_t AGG_B   = (size_t)3 * NB * 32 * 4;          // 25,165,824
    const size_t BINS_B  = (size_t)6 * NBUK * CAP * 8;       // 56,623,104
    const size_t CURS_B  = 8192;
    const size_t CSR_B   = (size_t)6 * NB * 4;               // 1,572,864
    const size_t CNT_B   = CSR_B;
    const size_t PCAT_B  = (size_t)2 * N_RELS * 32 * 4;
    const size_t PREL_B  = (size_t)N_RELS * 32 * 4;
    const size_t BPR_B   = 128;
    const size_t WSB_B   = (size_t)24 * 2 * 64 * 16;
    const bool fast = ws_size >= AGG_B + BINS_B + CURS_B + CSR_B + CNT_B
                                + PCAT_B + PREL_B + BPR_B + WSB_B;

    float* aggY = (float*)ws;
    size_t off = AGG_B;
    uint2* bins = nullptr; unsigned* cursor = nullptr; int *csr = nullptr, *cnt = nullptr;
    if (fast) {
        bins   = (uint2*)(ws + off);    off += BINS_B;
        cursor = (unsigned*)(ws + off); off += CURS_B;
        csr    = (int*)(ws + off);      off += CSR_B;
        cnt    = (int*)(ws + off);      off += CNT_B;
    }
    float* Pcat   = (float*)(ws + off); off += PCAT_B;
    float* Prel   = (float*)(ws + off); off += PREL_B;
    float* bprime = (float*)(ws + off); off += BPR_B;
    s16x8* wsB    = (s16x8*)(ws + off);

    k_prep<<<(3 * N_RELS + 7) / 8, 256, 0, stream>>>(rel_emb, W_in, b_in, W_out, b_out,
                                                     W_ent, b_ent, W_rel, b_rel,
                                                     Pcat, Prel, bprime);
    k_wfrag<<<12, 256, 0, stream>>>(W_ent, wsB);

    static const int base_idx[6] = {0, 3, 7, 10, 14, 17};
    if (fast) {
        Mats m;
        for (int i = 0; i < 6; ++i) {
            m.rows[i] = (const int*)d_in[base_idx[i]];
            m.cols[i] = (const int*)d_in[base_idx[i] + 1];
            m.vals[i] = (const float*)d_in[base_idx[i] + 2];
        }
        k_cursor<<<6, 256, 0, stream>>>(cursor);
        k_bin<<<6 * 256, 256, 0, stream>>>(m, bins, cursor);
        k_lfill<<<6 * NBUK, 256, 0, stream>>>(bins, cursor, csr, cnt);
        k_gather<<<3 * NB * 16 / 256, 256, 0, stream>>>(bins, csr, cnt, Pcat, aggY);
    } else {
        hipMemsetAsync(aggY, 0, AGG_B, stream);
        for (int mm = 0; mm < 6; ++mm) {
            const int d = mm & 1, s = mm >> 1;
            k_scatter<<<32768, 256, 0, stream>>>((const int*)d_in[base_idx[mm]],
                                                 (const int*)d_in[base_idx[mm] + 1],
                                                 (const float*)d_in[base_idx[mm] + 2],
                                                 Pcat + (size_t)d * N_RELS * 32,
                                                 aggY + (size_t)s * NB * 32);
        }
    }

    k_gemm<<<1536, 256, 0, stream>>>(feat_h, feat_p, feat_n, wsB, bprime, aggY);
    k_score<<<8192, 256, 0, stream>>>(aggY, eid, Prel, (float*)d_out);
}

// Round 10
// 370.816 us; speedup vs baseline: 3.9778x; 1.0119x over previous
//
#include <hip/hip_runtime.h>
#include <math.h>

#define N_RELS 1315
#define NB 65536
#define NNZV (1 << 20)
#define FEATD 768

#define NBUK 256       // row buckets (256 rows each)
#define CAP  4608      // bin capacity per (matrix,bucket); mean 4096, sigma 64 -> +8 sigma
#define CHUNK 4096     // edges per k_bin block
#define STG  2048      // edges per stage
#define EPT  8         // edges per thread per stage (256 threads)
#define MAXE 18        // CAP/256 per-thread edges in k_lfill

typedef float f32x4 __attribute__((ext_vector_type(4)));
typedef short s16x8 __attribute__((ext_vector_type(8)));
typedef float v2f  __attribute__((ext_vector_type(2)));

struct Mats { const int* rows[6]; const int* cols[6]; const float* vals[6]; };

__device__ __forceinline__ short f2bf(float f) {
    return __builtin_bit_cast(short, (__bf16)f);
}

// ---------------- precompute: P tables, Prel, b' ----------------
__global__ void k_prep(const float* __restrict__ rel_emb,
                       const float* __restrict__ W_in, const float* __restrict__ b_in,
                       const float* __restrict__ W_out, const float* __restrict__ b_out,
                       const float* __restrict__ W_ent, const float* __restrict__ b_ent,
                       const float* __restrict__ W_rel, const float* __restrict__ b_rel,
                       float* __restrict__ Pcat, float* __restrict__ Prel,
                       float* __restrict__ bprime)
{
    __shared__ float C[2][32][33];
    const int tid = threadIdx.x;
    for (int idx = tid; idx < 2 * 32 * 32; idx += 256) {
        int d = idx >> 10, o = (idx >> 5) & 31, t = idx & 31;
        const float* W  = d ? W_out : W_in;
        const float* we = W_ent + o * 832 + 768 + d * 32;
        float s = 0.f;
        #pragma unroll
        for (int j = 0; j < 32; ++j) s += we[j] * W[j * 32 + t];
        C[d][o][t] = s;
    }
    __syncthreads();

    const int row8 = blockIdx.x * 8 + (tid >> 5);
    const int o = tid & 31;
    if (row8 < 2 * N_RELS) {
        const int d = (row8 >= N_RELS) ? 1 : 0;
        const int r = row8 - d * N_RELS;
        const float* re = rel_emb + r * 32;
        float s = 0.f;
        #pragma unroll
        for (int t = 0; t < 32; ++t) s += re[t] * C[d][o][t];
        Pcat[row8 * 32 + o] = s;
    } else if (row8 < 3 * N_RELS) {
        const int r = row8 - 2 * N_RELS;
        const float* re = rel_emb + r * 32;
        float s = b_rel[o];
        #pragma unroll
        for (int j = 0; j < 32; ++j) s += W_rel[o * 32 + j] * re[j];
        float sq = s * s;
        #pragma unroll
        for (int m = 16; m; m >>= 1) sq += __shfl_xor(sq, m);
        Prel[r * 32 + o] = s / fmaxf(sqrtf(sq), 1e-12f);
    }
    if (blockIdx.x == 0 && tid < 32) {
        float s = b_ent[tid];
        #pragma unroll
        for (int j = 0; j < 32; ++j)
            s += b_in[j] * W_ent[tid * 832 + 768 + j] + b_out[j] * W_ent[tid * 832 + 800 + j];
        bprime[tid] = s;
    }
}

// ---------------- pack W_ent[:, :768] into bf16 B-fragments ----------------
__global__ void k_wfrag(const float* __restrict__ W_ent, s16x8* __restrict__ wsB)
{
    const int t = blockIdx.x * 256 + threadIdx.x;
    if (t >= 24 * 2 * 64) return;
    const int kk = t >> 7, rem = t & 127, nt = rem >> 6, l = rem & 63;
    const int col = nt * 16 + (l & 15);
    const int k0  = kk * 32 + ((l >> 4) << 3);
    const float* w = W_ent + col * 832 + k0;
    s16x8 v;
    #pragma unroll
    for (int e = 0; e < 8; ++e) v[e] = f2bf(w[e]);
    wsB[t] = v;
}

// ---------------- cursor init ----------------
__global__ void k_cursor(unsigned* __restrict__ cursor)
{
    const int i = blockIdx.x * 256 + threadIdx.x;
    if (i < 6 * NBUK) cursor[i] = (unsigned)i * CAP;
}

// ---------------- bin edges by row bucket ----------------
__global__ __launch_bounds__(256) void k_bin(Mats m, uint2* __restrict__ bins,
                                             unsigned* __restrict__ cursor)
{
    __shared__ unsigned lcnt[NBUK];
    __shared__ unsigned gbase[NBUK];
    const int mm    = blockIdx.x >> 8;      // 6 matrices x 256 chunks
    const int chunk = blockIdx.x & 255;
    const int tid   = threadIdx.x;
    const int* __restrict__ R = m.rows[mm];
    const int* __restrict__ C = m.cols[mm];
    const float* __restrict__ V = m.vals[mm];
    const int base = chunk * CHUNK;

    for (int st = 0; st < CHUNK / STG; ++st) {
        for (int i = tid; i < NBUK; i += 256) lcnt[i] = 0;
        __syncthreads();
        unsigned meta[EPT]; float val[EPT]; unsigned short lrank[EPT]; unsigned char buk[EPT];
        #pragma unroll
        for (int e = 0; e < EPT; ++e) {
            const int idx = base + st * STG + e * 256 + tid;
            const int row = R[idx];
            const int col = C[idx];
            val[e]  = V[idx];
            buk[e]  = (unsigned char)(row >> 8);
            meta[e] = ((unsigned)(row & 255) << 11) | (unsigned)col;
            lrank[e] = (unsigned short)atomicAdd(&lcnt[buk[e]], 1u);
        }
        __syncthreads();
        gbase[tid] = atomicAdd(&cursor[mm * NBUK + tid], lcnt[tid]);
        __syncthreads();
        #pragma unroll
        for (int e = 0; e < EPT; ++e)
            bins[gbase[buk[e]] + lrank[e]] = make_uint2(meta[e], __float_as_uint(val[e]));
        __syncthreads();
    }
}

// ---------------- bucket-local CSR fill (in-place, line-local writes) ----------------
__global__ __launch_bounds__(256) void k_lfill(uint2* __restrict__ bins,
                                               const unsigned* __restrict__ cursor,
                                               int* __restrict__ csr,
                                               int* __restrict__ cnt)
{
    __shared__ int hist[256];
    __shared__ int sc[256];
    __shared__ int ofs[256];
    const int mb = blockIdx.x;                 // mm*NBUK + b
    const unsigned segbase = (unsigned)mb * CAP;
    uint2* __restrict__ seg = bins + segbase;
    const int len = (int)(cursor[mb] - segbase);
    const int t = threadIdx.x;

    hist[t] = 0;
    __syncthreads();

    uint2 e[MAXE];
    #pragma unroll
    for (int j = 0; j < MAXE; ++j) {
        const int i = t + j * 256;
        if (i < len) e[j] = seg[i];
    }
    #pragma unroll
    for (int j = 0; j < MAXE; ++j) {
        const int i = t + j * 256;
        if (i < len) atomicAdd(&hist[e[j].x >> 11], 1);
    }
    __syncthreads();          // also drains all seg reads (vmcnt before barrier)

    sc[t] = hist[t];
    __syncthreads();
    for (int off = 1; off < 256; off <<= 1) {
        const int x = (t >= off) ? sc[t - off] : 0;
        __syncthreads();
        sc[t] += x;
        __syncthreads();
    }
    const int excl = t ? sc[t - 1] : 0;
    ofs[t] = excl;
    const int mm = mb >> 8, b = mb & 255;
    csr[mm * NB + b * 256 + t] = (int)segbase + excl;
    cnt[mm * NB + b * 256 + t] = hist[t];
    __syncthreads();

    #pragma unroll
    for (int j = 0; j < MAXE; ++j) {
        const int i = t + j * 256;
        if (i < len) {
            const int pos = atomicAdd(&ofs[e[j].x >> 11], 1);
            seg[pos] = make_uint2(e[j].x & 2047u, e[j].y);
        }
    }
}

// ---------------- gather: aggY[set][row][c] = sum of val*P, both dirs ----------------
__global__ __launch_bounds__(256) void k_gather(const uint2* __restrict__ slots,
                                                const int* __restrict__ csr,
                                                const int* __restrict__ cnt,
                                                const float* __restrict__ Pcat,
                                                float* __restrict__ aggY)
{
    const int tid = blockIdx.x * 256 + threadIdx.x;   // 3*NB*16 = 3*2^20
    const int pp  = tid & 15;
    const int row = (tid >> 4) & (NB - 1);
    const int set = tid >> 20;
    const int c2  = pp << 1;

    const int m0 = set * 2, m1 = m0 + 1;
    const int b0 = csr[m0 * NB + row], d0 = cnt[m0 * NB + row];
    const int b1 = csr[m1 * NB + row], d1 = cnt[m1 * NB + row];
    const uint2* __restrict__ s0 = slots + b0;
    const uint2* __restrict__ s1 = slots + b1;
    const float* __restrict__ P0 = Pcat + c2;
    const float* __restrict__ P1 = Pcat + (size_t)N_RELS * 32 + c2;

    float ax = 0.f, ay = 0.f, bx = 0.f, by = 0.f;
    const int dm = max(d0, d1);
    for (int j = 0; j < dm; j += 2) {
        uint2 ea0 = make_uint2(0u, 0u), ea1 = ea0, eb0 = ea0, eb1 = ea0;
        if (j     < d0) ea0 = s0[j];
        if (j + 1 < d0) ea1 = s0[j + 1];
        if (j     < d1) eb0 = s1[j];
        if (j + 1 < d1) eb1 = s1[j + 1];
        const float2 pa0 = *reinterpret_cast<const float2*>(P0 + (ea0.x << 5));
        const float2 pa1 = *reinterpret_cast<const float2*>(P0 + (ea1.x << 5));
        const float2 pb0 = *reinterpret_cast<const float2*>(P1 + (eb0.x << 5));
        const float2 pb1 = *reinterpret_cast<const float2*>(P1 + (eb1.x << 5));
        const float va0 = __uint_as_float(ea0.y), va1 = __uint_as_float(ea1.y);
        const float vb0 = __uint_as_float(eb0.y), vb1 = __uint_as_float(eb1.y);
        ax += va0 * pa0.x + va1 * pa1.x;  ay += va0 * pa0.y + va1 * pa1.y;
        bx += vb0 * pb0.x + vb1 * pb1.x;  by += vb0 * pb0.y + vb1 * pb1.y;
    }
    float2 r; r.x = ax + bx; r.y = ay + by;
    *reinterpret_cast<float2*>(aggY + ((size_t)set * NB + row) * 32 + c2) = r;
}

// ---------------- fallback scatter (ws too small) ----------------
__global__ void k_scatter(const int* __restrict__ rows, const int* __restrict__ cols,
                          const float* __restrict__ vals,
                          const float* __restrict__ Ptab, float* __restrict__ accs)
{
    const int stride = gridDim.x * blockDim.x;
    const int total = NNZV << 4;
    for (int g = blockIdx.x * blockDim.x + threadIdx.x; g < total; g += stride) {
        const int c2 = (g & 15) << 1;
        const int i  = g >> 4;
        const int row = rows[i];
        const int col = cols[i];
        const float v = vals[i];
        const float* p = Ptab + (col << 5) + c2;
        const int dst = (row << 5) + c2;
#if defined(__has_builtin) && __has_builtin(__builtin_amdgcn_global_atomic_fadd_v2f32)
        typedef __attribute__((address_space(1))) v2f* v2f_as1;
        v2f pv; pv.x = v * p[0]; pv.y = v * p[1];
        __builtin_amdgcn_global_atomic_fadd_v2f32(
            (v2f_as1)(unsigned long long)(accs + dst), pv);
#else
        atomicAdd(accs + dst,     v * p[0]);
        atomicAdd(accs + dst + 1, v * p[1]);
#endif
    }
}

// ---------------- GEMM v3: asm-pipelined A loads (4 deep), B in LDS ----------------
// Y[set] = normalize(feat @ W.T + b' + agg), in-place over aggY.
// A-loads are inline-asm global_load_dwordx4 with manual s_waitcnt vmcnt(N):
// the compiler cannot sink them. vmcnt queue holds ONLY these loads (B comes
// from LDS; bprime read before the staging barrier; barrier drains vm queue).

#define GLOAD2(BA, BB, OFF) \
    asm volatile("global_load_dwordx4 %0, %2, off offset:%3\n\t" \
                 "global_load_dwordx4 %1, %2, off offset:%4" \
                 : "=&v"(BA), "=&v"(BB) \
                 : "v"(abase), "n"(OFF), "n"((OFF) + 16) : "memory")

#define GSTEP(KK, BA, BB) do { \
    asm volatile("s_waitcnt vmcnt(%0)" \
                 :: "n"(2 * ((((KK) + 4 < 24) ? (KK) + 4 : 24) - (KK) - 1)) : "memory"); \
    __builtin_amdgcn_sched_barrier(0); \
    s16x8 av; \
    av[0] = f2bf(BA.x); av[1] = f2bf(BA.y); av[2] = f2bf(BA.z); av[3] = f2bf(BA.w); \
    av[4] = f2bf(BB.x); av[5] = f2bf(BB.y); av[6] = f2bf(BB.z); av[7] = f2bf(BB.w); \
    const s16x8 wb0 = lwp[((KK) * 2 + 0) << 6]; \
    const s16x8 wb1 = lwp[((KK) * 2 + 1) << 6]; \
    acc0 = __builtin_amdgcn_mfma_f32_16x16x32_bf16(av, wb0, acc0, 0, 0, 0); \
    acc1 = __builtin_amdgcn_mfma_f32_16x16x32_bf16(av, wb1, acc1, 0, 0, 0); \
    if ((KK) + 4 < 24) { GLOAD2(BA, BB, ((KK) + 4) * 128); } \
} while (0)

__global__ __launch_bounds__(512) void k_gemm(
    const float* __restrict__ feat_h, const float* __restrict__ feat_p,
    const float* __restrict__ feat_n,
    const s16x8* __restrict__ wsB, const float* __restrict__ bprime,
    float* __restrict__ Y)
{
    __shared__ s16x8 lwb[24 * 2 * 64];   // 48 KB
    const int tid  = threadIdx.x;
    const int lane = tid & 63;
    const int gwid = blockIdx.x * 8 + (tid >> 6);   // 0..12287
    const int set  = gwid >> 12;                    // 4096 tiles/set
    const int tile = gwid & 4095;
    const int e0   = tile << 4;                     // 16 entities
    const float* feat = (set == 0) ? feat_h : ((set == 1) ? feat_p : feat_n);

    const int l15 = lane & 15;
    const int kq  = lane >> 4;

    // read bprime BEFORE the barrier so its load is drained from the vm queue
    const float bp0 = bprime[l15], bp1 = bprime[l15 + 16];

    // stage all B-fragments to LDS (coalesced), then barrier (drains vmcnt)
    for (int i = tid; i < 3072; i += 512)
        reinterpret_cast<uint4*>(lwb)[i] = reinterpret_cast<const uint4*>(wsB)[i];
    __syncthreads();

    const float* abase = feat + (size_t)(e0 + l15) * FEATD + (kq << 3);
    const s16x8* lwp = lwb + lane;

    f32x4 acc0 = {0.f, 0.f, 0.f, 0.f};
    f32x4 acc1 = {0.f, 0.f, 0.f, 0.f};

    float4 a0, a1, a2, a3, c0, c1, c2, c3;
    GLOAD2(a0, c0, 0 * 128);
    GLOAD2(a1, c1, 1 * 128);
    GLOAD2(a2, c2, 2 * 128);
    GLOAD2(a3, c3, 3 * 128);

    GSTEP( 0, a0, c0); GSTEP( 1, a1, c1); GSTEP( 2, a2, c2); GSTEP( 3, a3, c3);
    GSTEP( 4, a0, c0); GSTEP( 5, a1, c1); GSTEP( 6, a2, c2); GSTEP( 7, a3, c3);
    GSTEP( 8, a0, c0); GSTEP( 9, a1, c1); GSTEP(10, a2, c2); GSTEP(11, a3, c3);
    GSTEP(12, a0, c0); GSTEP(13, a1, c1); GSTEP(14, a2, c2); GSTEP(15, a3, c3);
    GSTEP(16, a0, c0); GSTEP(17, a1, c1); GSTEP(18, a2, c2); GSTEP(19, a3, c3);
    GSTEP(20, a0, c0); GSTEP(21, a1, c1); GSTEP(22, a2, c2); GSTEP(23, a3, c3);

    float* yrow = Y + (size_t)set * NB * 32;
    const int rbase = e0 + (kq << 2);
    #pragma unroll
    for (int e = 0; e < 4; ++e) {
        const int ent = rbase + e;
        float v0 = acc0[e] + bp0 + yrow[ent * 32 + l15];
        float v1 = acc1[e] + bp1 + yrow[ent * 32 + l15 + 16];
        float sq = v0 * v0 + v1 * v1;
        sq += __shfl_xor(sq, 1);
        sq += __shfl_xor(sq, 2);
        sq += __shfl_xor(sq, 4);
        sq += __shfl_xor(sq, 8);
        const float inv = 1.f / fmaxf(sqrtf(sq), 1e-12f);
        yrow[ent * 32 + l15]      = v0 * inv;
        yrow[ent * 32 + l15 + 16] = v1 * inv;
    }
}

// ---------------- scores ----------------
__global__ __launch_bounds__(256) void k_score(const float* __restrict__ Y,
                                               const int* __restrict__ eid,
                                               const float* __restrict__ Prel,
                                               float* __restrict__ out)
{
    const int tid = blockIdx.x * 256 + threadIdx.x;
    const int ent = tid >> 5;
    const int c   = tid & 31;
    const float yh = Y[((size_t)0 * NB + ent) * 32 + c];
    const float yp = Y[((size_t)1 * NB + ent) * 32 + c];
    const float yn = Y[((size_t)2 * NB + ent) * 32 + c];
    const float r  = Prel[(size_t)eid[ent] * 32 + c];
    const float dp = yh + r - yp;
    const float dn = yh + r - yn;
    float sp = dp * dp, sn = dn * dn;
    #pragma unroll
    for (int m = 1; m <= 16; m <<= 1) { sp += __shfl_xor(sp, m); sn += __shfl_xor(sn, m); }
    if (c == 0) { out[ent] = sqrtf(sp); out[NB + ent] = sqrtf(sn); }
}

extern "C" void kernel_launch(void* const* d_in, const int* in_sizes, int n_in,
                              void* d_out, int out_size, void* d_ws, size_t ws_size,
                              hipStream_t stream)
{
    const float* feat_h = (const float*)d_in[6];
    const float* feat_p = (const float*)d_in[13];
    const float* feat_n = (const float*)d_in[20];
    const int*   eid    = (const int*)d_in[21];
    const float* rel_emb = (const float*)d_in[22];
    const float* W_in  = (const float*)d_in[23];
    const float* b_in  = (const float*)d_in[24];
    const float* W_out = (const float*)d_in[25];
    const float* b_out = (const float*)d_in[26];
    const float* W_ent = (const float*)d_in[27];
    const float* b_ent = (const float*)d_in[28];
    const float* W_rel = (const float*)d_in[29];
    const float* b_rel = (const float*)d_in[30];

    char* ws = (char*)d_ws;
    const size_t AGG_B   = (size_t)3 * NB * 32 * 4;          // 25,165,824
    const size_t BINS_B  = (size_t)6 * NBUK * CAP * 8;       // 56,623,104
    const size_t CURS_B  = 8192;
    const size_t CSR_B   = (size_t)6 * NB * 4;               // 1,572,864
    const size_t CNT_B   = CSR_B;
    const size_t PCAT_B  = (size_t)2 * N_RELS * 32 * 4;
    const size_t PREL_B  = (size_t)N_RELS * 32 * 4;
    const size_t BPR_B   = 128;
    const size_t WSB_B   = (size_t)24 * 2 * 64 * 16;
    const bool fast = ws_size >= AGG_B + BINS_B + CURS_B + CSR_B + CNT_B
                                + PCAT_B + PREL_B + BPR_B + WSB_B;

    float* aggY = (float*)ws;
    size_t off = AGG_B;
    uint2* bins = nullptr; unsigned* cursor = nullptr; int *csr = nullptr, *cnt = nullptr;
    if (fast) {
        bins   = (uint2*)(ws + off);    off += BINS_B;
        cursor = (unsigned*)(ws + off); off += CURS_B;
        csr    = (int*)(ws + off);      off += CSR_B;
        cnt    = (int*)(ws + off);      off += CNT_B;
    }
    float* Pcat   = (float*)(ws + off); off += PCAT_B;
    float* Prel   = (float*)(ws + off); off += PREL_B;
    float* bprime = (float*)(ws + off); off += BPR_B;
    s16x8* wsB    = (s16x8*)(ws + off);

    k_prep<<<(3 * N_RELS + 7) / 8, 256, 0, stream>>>(rel_emb, W_in, b_in, W_out, b_out,
                                                     W_ent, b_ent, W_rel, b_rel,
                                                     Pcat, Prel, bprime);
    k_wfrag<<<12, 256, 0, stream>>>(W_ent, wsB);

    static const int base_idx[6] = {0, 3, 7, 10, 14, 17};
    if (fast) {
        Mats m;
        for (int i = 0; i < 6; ++i) {
            m.rows[i] = (const int*)d_in[base_idx[i]];
            m.cols[i] = (const int*)d_in[base_idx[i] + 1];
            m.vals[i] = (const float*)d_in[base_idx[i] + 2];
        }
        k_cursor<<<6, 256, 0, stream>>>(cursor);
        k_bin<<<6 * 256, 256, 0, stream>>>(m, bins, cursor);
        k_lfill<<<6 * NBUK, 256, 0, stream>>>(bins, cursor, csr, cnt);
        k_gather<<<3 * NB * 16 / 256, 256, 0, stream>>>(bins, csr, cnt, Pcat, aggY);
    } else {
        hipMemsetAsync(aggY, 0, AGG_B, stream);
        for (int mm = 0; mm < 6; ++mm) {
            const int d = mm & 1, s = mm >> 1;
            k_scatter<<<32768, 256, 0, stream>>>((const int*)d_in[base_idx[mm]],
                                                 (const int*)d_in[base_idx[mm] + 1],
                                                 (const float*)d_in[base_idx[mm] + 2],
                                                 Pcat + (size_t)d * N_RELS * 32,
                                                 aggY + (size_t)s * NB * 32);
        }
    }

    k_gemm<<<1536, 512, 0, stream>>>(feat_h, feat_p, feat_n, wsB, bprime, aggY);
    k_score<<<8192, 256, 0, stream>>>(aggY, eid, Prel, (float*)d_out);
}